// Round 2
// baseline (2137.184 us; speedup 1.0000x reference)
//
#include <hip/hip_runtime.h>

typedef __bf16 bf16x8 __attribute__((ext_vector_type(8)));
typedef float f32x4 __attribute__((ext_vector_type(4)));

__device__ __forceinline__ float bf2f(unsigned short u) {
  return __uint_as_float(((unsigned)u) << 16);
}
__device__ __forceinline__ unsigned short f2bf(float f) {
  unsigned u = __float_as_uint(f);
  return (unsigned short)((u + 0x7fffu + ((u >> 16) & 1u)) >> 16);
}
__device__ __forceinline__ unsigned pack2(float a, float b) {
  return (unsigned)f2bf(a) | ((unsigned)f2bf(b) << 16);
}

// ---------------- lambda scalar ----------------
__global__ void lambda_kernel(const float* __restrict__ lq1, const float* __restrict__ lq2,
                              const float* __restrict__ lk1, const float* __restrict__ lk2,
                              float* __restrict__ out, float lam_init) {
  int l = threadIdx.x;
  float p1 = lq1[l] * lk1[l];
  float p2 = lq2[l] * lk2[l];
  #pragma unroll
  for (int off = 32; off; off >>= 1) {
    p1 += __shfl_xor(p1, off);
    p2 += __shfl_xor(p2, off);
  }
  if (l == 0) out[0] = expf(p1) - expf(p2) + lam_init;
}

// ---------------- GEMM: C[m][n] = sum_k A[m][k] * Bw[n][k] ----------------
// bf16 MFMA 16x16x32; 128x128 tile, BK=32, 4 waves (2x2), 4x4 frags/wave.
template <typename T>
__device__ __forceinline__ void stage16(const T* __restrict__ g, unsigned short* l) {
  if constexpr (sizeof(T) == 4) {
    #pragma unroll
    for (int p = 0; p < 4; ++p) {
      float4 v = reinterpret_cast<const float4*>(g)[p];
      uint2 pk;
      pk.x = pack2(v.x, v.y);
      pk.y = pack2(v.z, v.w);
      *reinterpret_cast<uint2*>(l + p * 4) = pk;
    }
  } else {
    const uint4* s = reinterpret_cast<const uint4*>(g);
    uint4 a = s[0], b = s[1];
    *reinterpret_cast<uint4*>(l) = a;
    *reinterpret_cast<uint4*>(l + 8) = b;
  }
}

template <typename AT, typename BT, typename OT>
__global__ __launch_bounds__(256)
void gemm_bt(const AT* __restrict__ A, const BT* __restrict__ Bw, OT* __restrict__ C,
             int M, int N, int K) {
  __shared__ __align__(16) unsigned short As[128 * 32];
  __shared__ __align__(16) unsigned short Bs[128 * 32];
  const int tid = threadIdx.x;
  const int bm = blockIdx.x * 128, bn = blockIdx.y * 128;
  const int lane = tid & 63, wave = tid >> 6;
  const int wm = (wave >> 1) * 64, wn = (wave & 1) * 64;
  const int srow = tid >> 1, shalf = (tid & 1) * 16;
  const int kf = (lane >> 4) * 8, rr = lane & 15;
  f32x4 acc[4][4] = {};
  for (int kt = 0; kt < K; kt += 32) {
    __syncthreads();
    stage16(&A[(long)(bm + srow) * K + kt + shalf], &As[srow * 32 + shalf]);
    stage16(&Bw[(long)(bn + srow) * K + kt + shalf], &Bs[srow * 32 + shalf]);
    __syncthreads();
    bf16x8 af[4], bq[4];
    #pragma unroll
    for (int i = 0; i < 4; ++i)
      af[i] = *reinterpret_cast<const bf16x8*>(&As[(wm + i * 16 + rr) * 32 + kf]);
    #pragma unroll
    for (int j = 0; j < 4; ++j)
      bq[j] = *reinterpret_cast<const bf16x8*>(&Bs[(wn + j * 16 + rr) * 32 + kf]);
    #pragma unroll
    for (int i = 0; i < 4; ++i)
      #pragma unroll
      for (int j = 0; j < 4; ++j)
        acc[i][j] = __builtin_amdgcn_mfma_f32_16x16x32_bf16(af[i], bq[j], acc[i][j], 0, 0, 0);
  }
  const int r0 = (lane >> 4) * 4, c0 = lane & 15;
  #pragma unroll
  for (int i = 0; i < 4; ++i)
    #pragma unroll
    for (int j = 0; j < 4; ++j) {
      #pragma unroll
      for (int r = 0; r < 4; ++r) {
        long row = bm + wm + i * 16 + r0 + r;
        long col = bn + wn + j * 16 + c0;
        float v = acc[i][j][r];
        if constexpr (sizeof(OT) == 2) C[row * N + col] = f2bf(v);
        else                           C[row * N + col] = v;
      }
    }
}

// ---------------- RoPE (+optional rel_pos pre-scale), with transpose ----------------
// in : raw proj bf16 [(b*1024+t)*2048 + hp*64 + d]   (b,t,hp,d)
// out: bf16 [((b*32+hp)*1024+t)*64 + d]              (b,hp,t,d)
__global__ __launch_bounds__(256) void rope_kernel(const unsigned short* __restrict__ raw,
                                                   const float* __restrict__ rel,
                                                   unsigned short* __restrict__ out,
                                                   int use_rel) {
  int idx = blockIdx.x * 256 + threadIdx.x;  // 2^21 total
  int i = idx & 31;
  int t = (idx >> 5) & 1023;
  int hp = (idx >> 15) & 31;
  int b = idx >> 20;
  int src = (b * 1024 + t) * 2048 + hp * 64 + 2 * i;
  unsigned pair = *reinterpret_cast<const unsigned*>(&raw[src]);
  float x1 = __uint_as_float(pair << 16);
  float x2 = __uint_as_float(pair & 0xffff0000u);
  if (use_rel) {
    x1 *= rel[t * 64 + 2 * i];
    x2 *= rel[t * 64 + 2 * i + 1];
  }
  float inv = expf(-0.28782313662425574f * (float)i);  // 10000^(-2i/64)
  float ang = (float)t * inv;
  float s, c;
  sincosf(ang, &s, &c);
  float r1 = x1 * c - x2 * s;
  float r2 = x1 * s + x2 * c;
  int dst = ((b * 32 + hp) * 1024 + t) * 64 + 2 * i;
  *reinterpret_cast<unsigned*>(&out[dst]) = pack2(r1, r2);
}

// ---------------- differential flash attention + fused sub-LN ----------------
#define QB 16
#define KB 64
__global__ __launch_bounds__(256) void attn_kernel(
    const unsigned short* __restrict__ Qa,  // (B,32,T,64) bf16
    const unsigned short* __restrict__ Ka,  // (B,32,T,64) bf16
    const unsigned short* __restrict__ Vr,  // (B,T,2048) bf16 raw-proj layout
    const float* __restrict__ lam_p,
    const float* __restrict__ subln,        // 128
    unsigned short* __restrict__ O) {       // (B,T,2048) bf16
  const int qt = blockIdx.x, h = blockIdx.y, b = blockIdx.z;
  const int tid = threadIdx.x;
  __shared__ __align__(16) float Qs[2][QB][64];
  __shared__ __align__(16) unsigned short Ks[2][KB][64];
  __shared__ __align__(16) unsigned short Vs[KB][128];
  __shared__ float S[2][QB][KB];
  __shared__ float mrow[2][QB], lrow[2][QB], rrow[2][QB];

  const float lam = lam_p[0];
  const int q0 = qt * QB;

  // load Q tiles (both sub-heads), pre-scaled by 1/sqrt(D)=1/8
  for (int e = tid; e < 2 * QB * 64; e += 256) {
    int hh = e >> 10;
    int qq = (e >> 6) & 15;
    int d = e & 63;
    float v = bf2f(Qa[((long)(b * 32 + 2 * h + hh) * 1024 + q0 + qq) * 64 + d]);
    Qs[hh][qq][d] = v * 0.125f;
  }
  if (tid < 2 * QB) {
    mrow[tid >> 4][tid & 15] = -1e30f;
    lrow[tid >> 4][tid & 15] = 0.f;
  }

  float o1[8], o2[8];
  #pragma unroll
  for (int j = 0; j < 8; ++j) { o1[j] = 0.f; o2[j] = 0.f; }
  const int oq = tid >> 4, oc = (tid & 15) * 8;

  const int ntiles = (q0 + QB - 1) / KB + 1;
  for (int tile = 0; tile < ntiles; ++tile) {
    const int k0 = tile * KB;
    __syncthreads();  // protect LDS from previous iteration's readers
    // stage K (2 heads x 64 x 64) as uint2
    for (int e = tid; e < 2 * KB * 16; e += 256) {
      int hh = e >> 10;
      int kk = (e >> 4) & 63;
      int dq = (e & 15) * 4;
      *reinterpret_cast<uint2*>(&Ks[hh][kk][dq]) = *reinterpret_cast<const uint2*>(
          &Ka[((long)(b * 32 + 2 * h + hh) * 1024 + k0 + kk) * 64 + dq]);
    }
    // stage V (64 x 128)
    for (int e = tid; e < KB * 32; e += 256) {
      int kk = e >> 5;
      int cq = (e & 31) * 4;
      *reinterpret_cast<uint2*>(&Vs[kk][cq]) = *reinterpret_cast<const uint2*>(
          &Vr[(long)(b * 1024 + k0 + kk) * 2048 + h * 128 + cq]);
    }
    __syncthreads();
    // scores: thread -> (sq, 4 consecutive ks), both heads
    {
      const int sq = tid >> 4;
      const int sk = (tid & 15) * 4;
      const int qglob = q0 + sq;
      float sa[4] = {0.f, 0.f, 0.f, 0.f}, sb[4] = {0.f, 0.f, 0.f, 0.f};
      for (int d = 0; d < 64; d += 4) {
        float4 qa = *reinterpret_cast<const float4*>(&Qs[0][sq][d]);
        float4 qb = *reinterpret_cast<const float4*>(&Qs[1][sq][d]);
        #pragma unroll
        for (int kk = 0; kk < 4; ++kk) {
          uint2 ka = *reinterpret_cast<const uint2*>(&Ks[0][sk + kk][d]);
          uint2 kb = *reinterpret_cast<const uint2*>(&Ks[1][sk + kk][d]);
          sa[kk] += qa.x * __uint_as_float(ka.x << 16) + qa.y * __uint_as_float(ka.x & 0xffff0000u) +
                    qa.z * __uint_as_float(ka.y << 16) + qa.w * __uint_as_float(ka.y & 0xffff0000u);
          sb[kk] += qb.x * __uint_as_float(kb.x << 16) + qb.y * __uint_as_float(kb.x & 0xffff0000u) +
                    qb.z * __uint_as_float(kb.y << 16) + qb.w * __uint_as_float(kb.y & 0xffff0000u);
        }
      }
      #pragma unroll
      for (int kk = 0; kk < 4; ++kk) {
        bool msk = (k0 + sk + kk) > qglob;
        S[0][sq][sk + kk] = msk ? -1e30f : sa[kk];
        S[1][sq][sk + kk] = msk ? -1e30f : sb[kk];
      }
    }
    __syncthreads();
    // online softmax per row: 32 rows, 8 threads each
    {
      const int row = tid >> 3, sub = tid & 7;
      const int hh = row >> 4, qq = row & 15;
      float mx = -1e30f;
      for (int kk = sub; kk < KB; kk += 8) mx = fmaxf(mx, S[hh][qq][kk]);
      #pragma unroll
      for (int off = 4; off; off >>= 1) mx = fmaxf(mx, __shfl_xor(mx, off));
      float mold = mrow[hh][qq];
      float mnew = fmaxf(mold, mx);
      float ls = 0.f;
      for (int kk = sub; kk < KB; kk += 8) {
        float p = __expf(S[hh][qq][kk] - mnew);  // masked: exp(-1e30-m) == 0
        S[hh][qq][kk] = p;
        ls += p;
      }
      #pragma unroll
      for (int off = 4; off; off >>= 1) ls += __shfl_xor(ls, off);
      if (sub == 0) {
        float resc = __expf(mold - mnew);
        lrow[hh][qq] = lrow[hh][qq] * resc + ls;
        mrow[hh][qq] = mnew;
        rrow[hh][qq] = resc;
      }
    }
    __syncthreads();
    // PV accumulate: thread -> (oq, 8 channels)
    {
      float rA = rrow[0][oq], rB = rrow[1][oq];
      #pragma unroll
      for (int j = 0; j < 8; ++j) { o1[j] *= rA; o2[j] *= rB; }
      for (int kk = 0; kk < KB; ++kk) {
        float pA = S[0][oq][kk], pB = S[1][oq][kk];
        uint4 vv = *reinterpret_cast<const uint4*>(&Vs[kk][oc]);
        float vf[8];
        vf[0] = __uint_as_float(vv.x << 16); vf[1] = __uint_as_float(vv.x & 0xffff0000u);
        vf[2] = __uint_as_float(vv.y << 16); vf[3] = __uint_as_float(vv.y & 0xffff0000u);
        vf[4] = __uint_as_float(vv.z << 16); vf[5] = __uint_as_float(vv.z & 0xffff0000u);
        vf[6] = __uint_as_float(vv.w << 16); vf[7] = __uint_as_float(vv.w & 0xffff0000u);
        #pragma unroll
        for (int j = 0; j < 8; ++j) { o1[j] += pA * vf[j]; o2[j] += pB * vf[j]; }
      }
    }
  }
  // epilogue: combine, RMS-norm over 128, subln scale, store bf16
  float lA = lrow[0][oq], lB = lrow[1][oq];
  float iA = 1.f / lA, iB = lam / lB;
  float at[8], ss = 0.f;
  #pragma unroll
  for (int j = 0; j < 8; ++j) {
    at[j] = o1[j] * iA - o2[j] * iB;
    ss += at[j] * at[j];
  }
  #pragma unroll
  for (int off = 8; off; off >>= 1) ss += __shfl_xor(ss, off);
  float scale = rsqrtf(ss * (1.f / 128.f) + 1e-5f);
  float vj[8];
  #pragma unroll
  for (int j = 0; j < 8; ++j) vj[j] = at[j] * scale * subln[oc + j];
  uint4 ow;
  ow.x = pack2(vj[0], vj[1]);
  ow.y = pack2(vj[2], vj[3]);
  ow.z = pack2(vj[4], vj[5]);
  ow.w = pack2(vj[6], vj[7]);
  const int qglob = q0 + oq;
  *reinterpret_cast<uint4*>(&O[(long)(b * 1024 + qglob) * 2048 + h * 128 + oc]) = ow;
}

extern "C" void kernel_launch(void* const* d_in, const int* in_sizes, int n_in,
                              void* d_out, int out_size, void* d_ws, size_t ws_size,
                              hipStream_t stream) {
  (void)in_sizes; (void)n_in; (void)out_size; (void)ws_size;
  const float* x    = (const float*)d_in[0];
  const float* rel  = (const float*)d_in[1];
  const float* wq   = (const float*)d_in[2];
  const float* wk   = (const float*)d_in[3];
  const float* wv   = (const float*)d_in[4];
  const float* lq1  = (const float*)d_in[5];
  const float* lq2  = (const float*)d_in[6];
  const float* lk1  = (const float*)d_in[7];
  const float* lk2  = (const float*)d_in[8];
  const float* subw = (const float*)d_in[9];
  const float* wo   = (const float*)d_in[10];
  float* out = (float*)d_out;

  char* ws = (char*)d_ws;
  const size_t SZ = (size_t)2048 * 2048 * 2;  // 8 MB (bf16 2048x2048)
  unsigned short* qraw = (unsigned short*)(ws);
  unsigned short* kraw = (unsigned short*)(ws + SZ);
  unsigned short* vraw = (unsigned short*)(ws + 2 * SZ);
  unsigned short* qatt = (unsigned short*)(ws + 3 * SZ);
  unsigned short* katt = (unsigned short*)(ws + 4 * SZ);
  float* lamb          = (float*)(ws + 5 * SZ);
  unsigned short* aout = qraw;  // qraw is dead after rope(q)

  // LAMBDA_INIT = 0.8 - 0.6*exp(-0.3*12)
  lambda_kernel<<<1, 64, 0, stream>>>(lq1, lq2, lk1, lk2, lamb, 0.7836057665316245f);

  dim3 gg(16, 16);
  gemm_bt<float, float, unsigned short><<<gg, 256, 0, stream>>>(x, wq, qraw, 2048, 2048, 2048);
  gemm_bt<float, float, unsigned short><<<gg, 256, 0, stream>>>(x, wk, kraw, 2048, 2048, 2048);
  gemm_bt<float, float, unsigned short><<<gg, 256, 0, stream>>>(x, wv, vraw, 2048, 2048, 2048);

  rope_kernel<<<8192, 256, 0, stream>>>(qraw, rel, qatt, 0);
  rope_kernel<<<8192, 256, 0, stream>>>(kraw, rel, katt, 1);

  attn_kernel<<<dim3(64, 16, 2), 256, 0, stream>>>(qatt, katt, vraw, lamb, subw, aout);

  gemm_bt<unsigned short, float, float><<<gg, 256, 0, stream>>>(aout, wo, out, 2048, 2048, 2048);
}

// Round 3
// 2136.692 us; speedup vs baseline: 1.0002x; 1.0002x over previous
//
#include <hip/hip_runtime.h>

typedef __bf16 bf16x8 __attribute__((ext_vector_type(8)));
typedef float f32x4 __attribute__((ext_vector_type(4)));

__device__ __forceinline__ float bf2f(unsigned short u) {
  return __uint_as_float(((unsigned)u) << 16);
}
__device__ __forceinline__ unsigned short f2bf(float f) {
  unsigned u = __float_as_uint(f);
  return (unsigned short)((u + 0x7fffu + ((u >> 16) & 1u)) >> 16);
}
__device__ __forceinline__ unsigned pack2(float a, float b) {
  return (unsigned)f2bf(a) | ((unsigned)f2bf(b) << 16);
}

// ---------------- lambda scalar ----------------
__global__ void lambda_kernel(const float* __restrict__ lq1, const float* __restrict__ lq2,
                              const float* __restrict__ lk1, const float* __restrict__ lk2,
                              float* __restrict__ out, float lam_init) {
  int l = threadIdx.x;
  float p1 = lq1[l] * lk1[l];
  float p2 = lq2[l] * lk2[l];
  #pragma unroll
  for (int off = 32; off; off >>= 1) {
    p1 += __shfl_xor(p1, off);
    p2 += __shfl_xor(p2, off);
  }
  if (l == 0) out[0] = expf(p1) - expf(p2) + lam_init;
}

// ---------------- GEMM: C[m][n] = sum_k A[m][k] * Bw[n][k] ----------------
// bf16 MFMA 16x16x32; 128x128 tile, BK=32, 4 waves (2x2), 4x4 frags/wave.
template <typename T>
__device__ __forceinline__ void stage16(const T* __restrict__ g, unsigned short* l) {
  if constexpr (sizeof(T) == 4) {
    #pragma unroll
    for (int p = 0; p < 4; ++p) {
      float4 v = reinterpret_cast<const float4*>(g)[p];
      uint2 pk;
      pk.x = pack2(v.x, v.y);
      pk.y = pack2(v.z, v.w);
      *reinterpret_cast<uint2*>(l + p * 4) = pk;
    }
  } else {
    const uint4* s = reinterpret_cast<const uint4*>(g);
    uint4 a = s[0], b = s[1];
    *reinterpret_cast<uint4*>(l) = a;
    *reinterpret_cast<uint4*>(l + 8) = b;
  }
}

template <typename AT, typename BT, typename OT>
__global__ __launch_bounds__(256)
void gemm_bt(const AT* __restrict__ A, const BT* __restrict__ Bw, OT* __restrict__ C,
             int M, int N, int K) {
  __shared__ __align__(16) unsigned short As[128 * 32];
  __shared__ __align__(16) unsigned short Bs[128 * 32];
  const int tid = threadIdx.x;
  const int bm = blockIdx.x * 128, bn = blockIdx.y * 128;
  const int lane = tid & 63, wave = tid >> 6;
  const int wm = (wave >> 1) * 64, wn = (wave & 1) * 64;
  const int srow = tid >> 1, shalf = (tid & 1) * 16;
  const int kf = (lane >> 4) * 8, rr = lane & 15;
  f32x4 acc[4][4] = {};
  for (int kt = 0; kt < K; kt += 32) {
    __syncthreads();
    stage16(&A[(long)(bm + srow) * K + kt + shalf], &As[srow * 32 + shalf]);
    stage16(&Bw[(long)(bn + srow) * K + kt + shalf], &Bs[srow * 32 + shalf]);
    __syncthreads();
    bf16x8 af[4], bq[4];
    #pragma unroll
    for (int i = 0; i < 4; ++i)
      af[i] = *reinterpret_cast<const bf16x8*>(&As[(wm + i * 16 + rr) * 32 + kf]);
    #pragma unroll
    for (int j = 0; j < 4; ++j)
      bq[j] = *reinterpret_cast<const bf16x8*>(&Bs[(wn + j * 16 + rr) * 32 + kf]);
    #pragma unroll
    for (int i = 0; i < 4; ++i)
      #pragma unroll
      for (int j = 0; j < 4; ++j)
        acc[i][j] = __builtin_amdgcn_mfma_f32_16x16x32_bf16(af[i], bq[j], acc[i][j], 0, 0, 0);
  }
  const int r0 = (lane >> 4) * 4, c0 = lane & 15;
  #pragma unroll
  for (int i = 0; i < 4; ++i)
    #pragma unroll
    for (int j = 0; j < 4; ++j) {
      #pragma unroll
      for (int r = 0; r < 4; ++r) {
        long row = bm + wm + i * 16 + r0 + r;
        long col = bn + wn + j * 16 + c0;
        float v = acc[i][j][r];
        if constexpr (sizeof(OT) == 2) C[row * N + col] = f2bf(v);
        else                           C[row * N + col] = v;
      }
    }
}

// ---------------- RoPE (+optional rel_pos pre-scale), with transpose ----------------
// in : raw proj bf16 [(b*1024+t)*2048 + hp*64 + d]   (b,t,hp,d)
// out: bf16 [((b*32+hp)*1024+t)*64 + d]              (b,hp,t,d)
__global__ __launch_bounds__(256) void rope_kernel(const unsigned short* __restrict__ raw,
                                                   const float* __restrict__ rel,
                                                   unsigned short* __restrict__ out,
                                                   int use_rel) {
  int idx = blockIdx.x * 256 + threadIdx.x;  // 2^21 total
  int i = idx & 31;
  int t = (idx >> 5) & 1023;
  int hp = (idx >> 15) & 31;
  int b = idx >> 20;
  int src = (b * 1024 + t) * 2048 + hp * 64 + 2 * i;
  unsigned pair = *reinterpret_cast<const unsigned*>(&raw[src]);
  float x1 = __uint_as_float(pair << 16);
  float x2 = __uint_as_float(pair & 0xffff0000u);
  if (use_rel) {
    x1 *= rel[t * 64 + 2 * i];
    x2 *= rel[t * 64 + 2 * i + 1];
  }
  float inv = expf(-0.28782313662425574f * (float)i);  // 10000^(-2i/64)
  float ang = (float)t * inv;
  float s, c;
  sincosf(ang, &s, &c);
  float r1 = x1 * c - x2 * s;
  float r2 = x1 * s + x2 * c;
  int dst = ((b * 32 + hp) * 1024 + t) * 64 + 2 * i;
  *reinterpret_cast<unsigned*>(&out[dst]) = pack2(r1, r2);
}

// ---------------- differential flash attention + fused sub-LN ----------------
#define QB 16
#define KB 64
__global__ __launch_bounds__(256) void attn_kernel(
    const unsigned short* __restrict__ Qa,  // (B,32,T,64) bf16
    const unsigned short* __restrict__ Ka,  // (B,32,T,64) bf16
    const unsigned short* __restrict__ Vr,  // (B,T,2048) bf16 raw-proj layout
    const float* __restrict__ lam_p,
    const float* __restrict__ subln,        // 128
    unsigned short* __restrict__ O) {       // (B,T,2048) bf16
  const int qt = blockIdx.x, h = blockIdx.y, b = blockIdx.z;
  const int tid = threadIdx.x;
  __shared__ __align__(16) float Qs[2][QB][64];
  __shared__ __align__(16) unsigned short Ks[2][KB][64];
  __shared__ __align__(16) unsigned short Vs[KB][128];
  __shared__ float S[2][QB][KB];
  __shared__ float mrow[2][QB], lrow[2][QB], rrow[2][QB];

  const float lam = lam_p[0];
  const int q0 = qt * QB;

  // load Q tiles (both sub-heads), pre-scaled by 1/sqrt(D)=1/8
  for (int e = tid; e < 2 * QB * 64; e += 256) {
    int hh = e >> 10;
    int qq = (e >> 6) & 15;
    int d = e & 63;
    float v = bf2f(Qa[((long)(b * 32 + 2 * h + hh) * 1024 + q0 + qq) * 64 + d]);
    Qs[hh][qq][d] = v * 0.125f;
  }
  if (tid < 2 * QB) {
    mrow[tid >> 4][tid & 15] = -1e30f;
    lrow[tid >> 4][tid & 15] = 0.f;
  }

  float o1[8], o2[8];
  #pragma unroll
  for (int j = 0; j < 8; ++j) { o1[j] = 0.f; o2[j] = 0.f; }
  const int oq = tid >> 4, oc = (tid & 15) * 8;

  const int ntiles = (q0 + QB - 1) / KB + 1;
  for (int tile = 0; tile < ntiles; ++tile) {
    const int k0 = tile * KB;
    __syncthreads();  // protect LDS from previous iteration's readers
    // stage K (2 heads x 64 x 64) as uint2
    for (int e = tid; e < 2 * KB * 16; e += 256) {
      int hh = e >> 10;
      int kk = (e >> 4) & 63;
      int dq = (e & 15) * 4;
      *reinterpret_cast<uint2*>(&Ks[hh][kk][dq]) = *reinterpret_cast<const uint2*>(
          &Ka[((long)(b * 32 + 2 * h + hh) * 1024 + k0 + kk) * 64 + dq]);
    }
    // stage V (64 x 128)
    for (int e = tid; e < KB * 32; e += 256) {
      int kk = e >> 5;
      int cq = (e & 31) * 4;
      *reinterpret_cast<uint2*>(&Vs[kk][cq]) = *reinterpret_cast<const uint2*>(
          &Vr[(long)(b * 1024 + k0 + kk) * 2048 + h * 128 + cq]);
    }
    __syncthreads();
    // scores: thread -> (sq, 4 consecutive ks), both heads
    {
      const int sq = tid >> 4;
      const int sk = (tid & 15) * 4;
      const int qglob = q0 + sq;
      float sa[4] = {0.f, 0.f, 0.f, 0.f}, sb[4] = {0.f, 0.f, 0.f, 0.f};
      for (int d = 0; d < 64; d += 4) {
        float4 qa = *reinterpret_cast<const float4*>(&Qs[0][sq][d]);
        float4 qb = *reinterpret_cast<const float4*>(&Qs[1][sq][d]);
        #pragma unroll
        for (int kk = 0; kk < 4; ++kk) {
          uint2 ka = *reinterpret_cast<const uint2*>(&Ks[0][sk + kk][d]);
          uint2 kb = *reinterpret_cast<const uint2*>(&Ks[1][sk + kk][d]);
          sa[kk] += qa.x * __uint_as_float(ka.x << 16) + qa.y * __uint_as_float(ka.x & 0xffff0000u) +
                    qa.z * __uint_as_float(ka.y << 16) + qa.w * __uint_as_float(ka.y & 0xffff0000u);
          sb[kk] += qb.x * __uint_as_float(kb.x << 16) + qb.y * __uint_as_float(kb.x & 0xffff0000u) +
                    qb.z * __uint_as_float(kb.y << 16) + qb.w * __uint_as_float(kb.y & 0xffff0000u);
        }
      }
      #pragma unroll
      for (int kk = 0; kk < 4; ++kk) {
        bool msk = (k0 + sk + kk) > qglob;
        S[0][sq][sk + kk] = msk ? -1e30f : sa[kk];
        S[1][sq][sk + kk] = msk ? -1e30f : sb[kk];
      }
    }
    __syncthreads();
    // online softmax per row: 32 rows, 8 threads each
    {
      const int row = tid >> 3, sub = tid & 7;
      const int hh = row >> 4, qq = row & 15;
      float mx = -1e30f;
      for (int kk = sub; kk < KB; kk += 8) mx = fmaxf(mx, S[hh][qq][kk]);
      #pragma unroll
      for (int off = 4; off; off >>= 1) mx = fmaxf(mx, __shfl_xor(mx, off));
      float mold = mrow[hh][qq];
      float mnew = fmaxf(mold, mx);
      float ls = 0.f;
      for (int kk = sub; kk < KB; kk += 8) {
        float p = __expf(S[hh][qq][kk] - mnew);  // masked: exp(-1e30-m) == 0
        S[hh][qq][kk] = p;
        ls += p;
      }
      #pragma unroll
      for (int off = 4; off; off >>= 1) ls += __shfl_xor(ls, off);
      if (sub == 0) {
        float resc = __expf(mold - mnew);
        lrow[hh][qq] = lrow[hh][qq] * resc + ls;
        mrow[hh][qq] = mnew;
        rrow[hh][qq] = resc;
      }
    }
    __syncthreads();
    // PV accumulate: thread -> (oq, 8 channels)
    {
      float rA = rrow[0][oq], rB = rrow[1][oq];
      #pragma unroll
      for (int j = 0; j < 8; ++j) { o1[j] *= rA; o2[j] *= rB; }
      for (int kk = 0; kk < KB; ++kk) {
        float pA = S[0][oq][kk], pB = S[1][oq][kk];
        uint4 vv = *reinterpret_cast<const uint4*>(&Vs[kk][oc]);
        float vf[8];
        vf[0] = __uint_as_float(vv.x << 16); vf[1] = __uint_as_float(vv.x & 0xffff0000u);
        vf[2] = __uint_as_float(vv.y << 16); vf[3] = __uint_as_float(vv.y & 0xffff0000u);
        vf[4] = __uint_as_float(vv.z << 16); vf[5] = __uint_as_float(vv.z & 0xffff0000u);
        vf[6] = __uint_as_float(vv.w << 16); vf[7] = __uint_as_float(vv.w & 0xffff0000u);
        #pragma unroll
        for (int j = 0; j < 8; ++j) { o1[j] += pA * vf[j]; o2[j] += pB * vf[j]; }
      }
    }
  }
  // epilogue: combine, RMS-norm over 128, subln scale, store bf16
  float lA = lrow[0][oq], lB = lrow[1][oq];
  float iA = 1.f / lA, iB = lam / lB;
  float at[8], ss = 0.f;
  #pragma unroll
  for (int j = 0; j < 8; ++j) {
    at[j] = o1[j] * iA - o2[j] * iB;
    ss += at[j] * at[j];
  }
  #pragma unroll
  for (int off = 8; off; off >>= 1) ss += __shfl_xor(ss, off);
  float scale = rsqrtf(ss * (1.f / 128.f) + 1e-5f);
  float vj[8];
  #pragma unroll
  for (int j = 0; j < 8; ++j) vj[j] = at[j] * scale * subln[oc + j];
  uint4 ow;
  ow.x = pack2(vj[0], vj[1]);
  ow.y = pack2(vj[2], vj[3]);
  ow.z = pack2(vj[4], vj[5]);
  ow.w = pack2(vj[6], vj[7]);
  const int qglob = q0 + oq;
  *reinterpret_cast<uint4*>(&O[(long)(b * 1024 + qglob) * 2048 + h * 128 + oc]) = ow;
}

extern "C" void kernel_launch(void* const* d_in, const int* in_sizes, int n_in,
                              void* d_out, int out_size, void* d_ws, size_t ws_size,
                              hipStream_t stream) {
  (void)in_sizes; (void)n_in; (void)out_size; (void)ws_size;
  const float* x    = (const float*)d_in[0];
  const float* rel  = (const float*)d_in[1];
  const float* wq   = (const float*)d_in[2];
  const float* wk   = (const float*)d_in[3];
  const float* wv   = (const float*)d_in[4];
  const float* lq1  = (const float*)d_in[5];
  const float* lq2  = (const float*)d_in[6];
  const float* lk1  = (const float*)d_in[7];
  const float* lk2  = (const float*)d_in[8];
  const float* subw = (const float*)d_in[9];
  const float* wo   = (const float*)d_in[10];
  float* out = (float*)d_out;

  char* ws = (char*)d_ws;
  const size_t SZ = (size_t)2048 * 2048 * 2;  // 8 MB (bf16 2048x2048)
  unsigned short* qraw = (unsigned short*)(ws);
  unsigned short* kraw = (unsigned short*)(ws + SZ);
  unsigned short* vraw = (unsigned short*)(ws + 2 * SZ);
  unsigned short* qatt = (unsigned short*)(ws + 3 * SZ);
  unsigned short* katt = (unsigned short*)(ws + 4 * SZ);
  float* lamb          = (float*)(ws + 5 * SZ);
  unsigned short* aout = qraw;  // qraw is dead after rope(q)

  // LAMBDA_INIT = 0.8 - 0.6*exp(-0.3*12)
  lambda_kernel<<<1, 64, 0, stream>>>(lq1, lq2, lk1, lk2, lamb, 0.7836057665316245f);

  dim3 gg(16, 16);
  gemm_bt<float, float, unsigned short><<<gg, 256, 0, stream>>>(x, wq, qraw, 2048, 2048, 2048);
  gemm_bt<float, float, unsigned short><<<gg, 256, 0, stream>>>(x, wk, kraw, 2048, 2048, 2048);
  gemm_bt<float, float, unsigned short><<<gg, 256, 0, stream>>>(x, wv, vraw, 2048, 2048, 2048);

  rope_kernel<<<8192, 256, 0, stream>>>(qraw, rel, qatt, 0);
  rope_kernel<<<8192, 256, 0, stream>>>(kraw, rel, katt, 1);

  attn_kernel<<<dim3(64, 16, 2), 256, 0, stream>>>(qatt, katt, vraw, lamb, subw, aout);

  gemm_bt<unsigned short, float, float><<<gg, 256, 0, stream>>>(aout, wo, out, 2048, 2048, 2048);
}

// Round 4
// 2125.483 us; speedup vs baseline: 1.0055x; 1.0053x over previous
//
#include <hip/hip_runtime.h>

typedef __bf16 bf16x8 __attribute__((ext_vector_type(8)));
typedef float f32x4 __attribute__((ext_vector_type(4)));

__device__ __forceinline__ float bf2f(unsigned short u) {
  return __uint_as_float(((unsigned)u) << 16);
}
__device__ __forceinline__ unsigned short f2bf(float f) {
  unsigned u = __float_as_uint(f);
  return (unsigned short)((u + 0x7fffu + ((u >> 16) & 1u)) >> 16);
}
__device__ __forceinline__ unsigned pack2(float a, float b) {
  return (unsigned)f2bf(a) | ((unsigned)f2bf(b) << 16);
}

// ---------------- lambda scalar ----------------
__global__ void lambda_kernel(const float* __restrict__ lq1, const float* __restrict__ lq2,
                              const float* __restrict__ lk1, const float* __restrict__ lk2,
                              float* __restrict__ out, float lam_init) {
  int l = threadIdx.x;
  float p1 = lq1[l] * lk1[l];
  float p2 = lq2[l] * lk2[l];
  #pragma unroll
  for (int off = 32; off; off >>= 1) {
    p1 += __shfl_xor(p1, off);
    p2 += __shfl_xor(p2, off);
  }
  if (l == 0) out[0] = expf(p1) - expf(p2) + lam_init;
}

// ---------------- GEMM: C[m][n] = sum_k A[m][k] * Bw[n][k] ----------------
// bf16 MFMA 16x16x32; 128x128 tile, BK=32, 4 waves (2x2), 4x4 frags/wave.
template <typename T>
__device__ __forceinline__ void stage16(const T* __restrict__ g, unsigned short* l) {
  if constexpr (sizeof(T) == 4) {
    #pragma unroll
    for (int p = 0; p < 4; ++p) {
      float4 v = reinterpret_cast<const float4*>(g)[p];
      uint2 pk;
      pk.x = pack2(v.x, v.y);
      pk.y = pack2(v.z, v.w);
      *reinterpret_cast<uint2*>(l + p * 4) = pk;
    }
  } else {
    const uint4* s = reinterpret_cast<const uint4*>(g);
    uint4 a = s[0], b = s[1];
    *reinterpret_cast<uint4*>(l) = a;
    *reinterpret_cast<uint4*>(l + 8) = b;
  }
}

template <typename AT, typename BT, typename OT>
__global__ __launch_bounds__(256)
void gemm_bt(const AT* __restrict__ A, const BT* __restrict__ Bw, OT* __restrict__ C,
             int M, int N, int K) {
  __shared__ __align__(16) unsigned short As[128 * 32];
  __shared__ __align__(16) unsigned short Bs[128 * 32];
  const int tid = threadIdx.x;
  const int bm = blockIdx.x * 128, bn = blockIdx.y * 128;
  const int lane = tid & 63, wave = tid >> 6;
  const int wm = (wave >> 1) * 64, wn = (wave & 1) * 64;
  const int srow = tid >> 1, shalf = (tid & 1) * 16;
  const int kf = (lane >> 4) * 8, rr = lane & 15;
  f32x4 acc[4][4] = {};
  for (int kt = 0; kt < K; kt += 32) {
    __syncthreads();
    stage16(&A[(long)(bm + srow) * K + kt + shalf], &As[srow * 32 + shalf]);
    stage16(&Bw[(long)(bn + srow) * K + kt + shalf], &Bs[srow * 32 + shalf]);
    __syncthreads();
    bf16x8 af[4], bq[4];
    #pragma unroll
    for (int i = 0; i < 4; ++i)
      af[i] = *reinterpret_cast<const bf16x8*>(&As[(wm + i * 16 + rr) * 32 + kf]);
    #pragma unroll
    for (int j = 0; j < 4; ++j)
      bq[j] = *reinterpret_cast<const bf16x8*>(&Bs[(wn + j * 16 + rr) * 32 + kf]);
    #pragma unroll
    for (int i = 0; i < 4; ++i)
      #pragma unroll
      for (int j = 0; j < 4; ++j)
        acc[i][j] = __builtin_amdgcn_mfma_f32_16x16x32_bf16(af[i], bq[j], acc[i][j], 0, 0, 0);
  }
  const int r0 = (lane >> 4) * 4, c0 = lane & 15;
  #pragma unroll
  for (int i = 0; i < 4; ++i)
    #pragma unroll
    for (int j = 0; j < 4; ++j) {
      #pragma unroll
      for (int r = 0; r < 4; ++r) {
        long row = bm + wm + i * 16 + r0 + r;
        long col = bn + wn + j * 16 + c0;
        float v = acc[i][j][r];
        if constexpr (sizeof(OT) == 2) C[row * N + col] = f2bf(v);
        else                           C[row * N + col] = v;
      }
    }
}

// ---------------- RoPE (+optional rel_pos pre-scale), with transpose ----------------
// in : raw proj bf16 [(b*1024+t)*2048 + hp*64 + d]   (b,t,hp,d)
// out: bf16 [((b*32+hp)*1024+t)*64 + d]              (b,hp,t,d)
__global__ __launch_bounds__(256) void rope_kernel(const unsigned short* __restrict__ raw,
                                                   const float* __restrict__ rel,
                                                   unsigned short* __restrict__ out,
                                                   int use_rel) {
  int idx = blockIdx.x * 256 + threadIdx.x;  // 2^21 total
  int i = idx & 31;
  int t = (idx >> 5) & 1023;
  int hp = (idx >> 15) & 31;
  int b = idx >> 20;
  int src = (b * 1024 + t) * 2048 + hp * 64 + 2 * i;
  unsigned pair = *reinterpret_cast<const unsigned*>(&raw[src]);
  float x1 = __uint_as_float(pair << 16);
  float x2 = __uint_as_float(pair & 0xffff0000u);
  if (use_rel) {
    x1 *= rel[t * 64 + 2 * i];
    x2 *= rel[t * 64 + 2 * i + 1];
  }
  float inv = expf(-0.28782313662425574f * (float)i);  // 10000^(-2i/64)
  float ang = (float)t * inv;
  float s, c;
  sincosf(ang, &s, &c);
  float r1 = x1 * c - x2 * s;
  float r2 = x1 * s + x2 * c;
  int dst = ((b * 32 + hp) * 1024 + t) * 64 + 2 * i;
  *reinterpret_cast<unsigned*>(&out[dst]) = pack2(r1, r2);
}

// ---------------- differential flash attention + fused sub-LN ----------------
#define QB 16
#define KB 64
__global__ __launch_bounds__(256) void attn_kernel(
    const unsigned short* __restrict__ Qa,  // (B,32,T,64) bf16
    const unsigned short* __restrict__ Ka,  // (B,32,T,64) bf16
    const unsigned short* __restrict__ Vr,  // (B,T,2048) bf16 raw-proj layout
    const float* __restrict__ lam_p,
    const float* __restrict__ subln,        // 128
    unsigned short* __restrict__ O) {       // (B,T,2048) bf16
  const int qt = blockIdx.x, h = blockIdx.y, b = blockIdx.z;
  const int tid = threadIdx.x;
  __shared__ __align__(16) float Qs[2][QB][64];
  __shared__ __align__(16) unsigned short Ks[2][KB][64];
  __shared__ __align__(16) unsigned short Vs[KB][128];
  __shared__ float S[2][QB][KB];
  __shared__ float mrow[2][QB], lrow[2][QB], rrow[2][QB];

  const float lam = lam_p[0];
  const int q0 = qt * QB;

  // load Q tiles (both sub-heads), pre-scaled by 1/sqrt(D)=1/8
  for (int e = tid; e < 2 * QB * 64; e += 256) {
    int hh = e >> 10;
    int qq = (e >> 6) & 15;
    int d = e & 63;
    float v = bf2f(Qa[((long)(b * 32 + 2 * h + hh) * 1024 + q0 + qq) * 64 + d]);
    Qs[hh][qq][d] = v * 0.125f;
  }
  if (tid < 2 * QB) {
    mrow[tid >> 4][tid & 15] = -1e30f;
    lrow[tid >> 4][tid & 15] = 0.f;
  }

  float o1[8], o2[8];
  #pragma unroll
  for (int j = 0; j < 8; ++j) { o1[j] = 0.f; o2[j] = 0.f; }
  const int oq = tid >> 4, oc = (tid & 15) * 8;

  const int ntiles = (q0 + QB - 1) / KB + 1;
  for (int tile = 0; tile < ntiles; ++tile) {
    const int k0 = tile * KB;
    __syncthreads();  // protect LDS from previous iteration's readers
    // stage K (2 heads x 64 x 64) as uint2
    for (int e = tid; e < 2 * KB * 16; e += 256) {
      int hh = e >> 10;
      int kk = (e >> 4) & 63;
      int dq = (e & 15) * 4;
      *reinterpret_cast<uint2*>(&Ks[hh][kk][dq]) = *reinterpret_cast<const uint2*>(
          &Ka[((long)(b * 32 + 2 * h + hh) * 1024 + k0 + kk) * 64 + dq]);
    }
    // stage V (64 x 128)
    for (int e = tid; e < KB * 32; e += 256) {
      int kk = e >> 5;
      int cq = (e & 31) * 4;
      *reinterpret_cast<uint2*>(&Vs[kk][cq]) = *reinterpret_cast<const uint2*>(
          &Vr[(long)(b * 1024 + k0 + kk) * 2048 + h * 128 + cq]);
    }
    __syncthreads();
    // scores: thread -> (sq, 4 consecutive ks), both heads
    {
      const int sq = tid >> 4;
      const int sk = (tid & 15) * 4;
      const int qglob = q0 + sq;
      float sa[4] = {0.f, 0.f, 0.f, 0.f}, sb[4] = {0.f, 0.f, 0.f, 0.f};
      for (int d = 0; d < 64; d += 4) {
        float4 qa = *reinterpret_cast<const float4*>(&Qs[0][sq][d]);
        float4 qb = *reinterpret_cast<const float4*>(&Qs[1][sq][d]);
        #pragma unroll
        for (int kk = 0; kk < 4; ++kk) {
          uint2 ka = *reinterpret_cast<const uint2*>(&Ks[0][sk + kk][d]);
          uint2 kb = *reinterpret_cast<const uint2*>(&Ks[1][sk + kk][d]);
          sa[kk] += qa.x * __uint_as_float(ka.x << 16) + qa.y * __uint_as_float(ka.x & 0xffff0000u) +
                    qa.z * __uint_as_float(ka.y << 16) + qa.w * __uint_as_float(ka.y & 0xffff0000u);
          sb[kk] += qb.x * __uint_as_float(kb.x << 16) + qb.y * __uint_as_float(kb.x & 0xffff0000u) +
                    qb.z * __uint_as_float(kb.y << 16) + qb.w * __uint_as_float(kb.y & 0xffff0000u);
        }
      }
      #pragma unroll
      for (int kk = 0; kk < 4; ++kk) {
        bool msk = (k0 + sk + kk) > qglob;
        S[0][sq][sk + kk] = msk ? -1e30f : sa[kk];
        S[1][sq][sk + kk] = msk ? -1e30f : sb[kk];
      }
    }
    __syncthreads();
    // online softmax per row: 32 rows, 8 threads each
    {
      const int row = tid >> 3, sub = tid & 7;
      const int hh = row >> 4, qq = row & 15;
      float mx = -1e30f;
      for (int kk = sub; kk < KB; kk += 8) mx = fmaxf(mx, S[hh][qq][kk]);
      #pragma unroll
      for (int off = 4; off; off >>= 1) mx = fmaxf(mx, __shfl_xor(mx, off));
      float mold = mrow[hh][qq];
      float mnew = fmaxf(mold, mx);
      float ls = 0.f;
      for (int kk = sub; kk < KB; kk += 8) {
        float p = __expf(S[hh][qq][kk] - mnew);  // masked: exp(-1e30-m) == 0
        S[hh][qq][kk] = p;
        ls += p;
      }
      #pragma unroll
      for (int off = 4; off; off >>= 1) ls += __shfl_xor(ls, off);
      if (sub == 0) {
        float resc = __expf(mold - mnew);
        lrow[hh][qq] = lrow[hh][qq] * resc + ls;
        mrow[hh][qq] = mnew;
        rrow[hh][qq] = resc;
      }
    }
    __syncthreads();
    // PV accumulate: thread -> (oq, 8 channels)
    {
      float rA = rrow[0][oq], rB = rrow[1][oq];
      #pragma unroll
      for (int j = 0; j < 8; ++j) { o1[j] *= rA; o2[j] *= rB; }
      for (int kk = 0; kk < KB; ++kk) {
        float pA = S[0][oq][kk], pB = S[1][oq][kk];
        uint4 vv = *reinterpret_cast<const uint4*>(&Vs[kk][oc]);
        float vf[8];
        vf[0] = __uint_as_float(vv.x << 16); vf[1] = __uint_as_float(vv.x & 0xffff0000u);
        vf[2] = __uint_as_float(vv.y << 16); vf[3] = __uint_as_float(vv.y & 0xffff0000u);
        vf[4] = __uint_as_float(vv.z << 16); vf[5] = __uint_as_float(vv.z & 0xffff0000u);
        vf[6] = __uint_as_float(vv.w << 16); vf[7] = __uint_as_float(vv.w & 0xffff0000u);
        #pragma unroll
        for (int j = 0; j < 8; ++j) { o1[j] += pA * vf[j]; o2[j] += pB * vf[j]; }
      }
    }
  }
  // epilogue: combine, RMS-norm over 128, subln scale, store bf16
  float lA = lrow[0][oq], lB = lrow[1][oq];
  float iA = 1.f / lA, iB = lam / lB;
  float at[8], ss = 0.f;
  #pragma unroll
  for (int j = 0; j < 8; ++j) {
    at[j] = o1[j] * iA - o2[j] * iB;
    ss += at[j] * at[j];
  }
  #pragma unroll
  for (int off = 8; off; off >>= 1) ss += __shfl_xor(ss, off);
  float scale = rsqrtf(ss * (1.f / 128.f) + 1e-5f);
  float vj[8];
  #pragma unroll
  for (int j = 0; j < 8; ++j) vj[j] = at[j] * scale * subln[oc + j];
  uint4 ow;
  ow.x = pack2(vj[0], vj[1]);
  ow.y = pack2(vj[2], vj[3]);
  ow.z = pack2(vj[4], vj[5]);
  ow.w = pack2(vj[6], vj[7]);
  const int qglob = q0 + oq;
  *reinterpret_cast<uint4*>(&O[(long)(b * 1024 + qglob) * 2048 + h * 128 + oc]) = ow;
}

extern "C" void kernel_launch(void* const* d_in, const int* in_sizes, int n_in,
                              void* d_out, int out_size, void* d_ws, size_t ws_size,
                              hipStream_t stream) {
  (void)in_sizes; (void)n_in; (void)out_size; (void)ws_size;
  const float* x    = (const float*)d_in[0];
  const float* rel  = (const float*)d_in[1];
  const float* wq   = (const float*)d_in[2];
  const float* wk   = (const float*)d_in[3];
  const float* wv   = (const float*)d_in[4];
  const float* lq1  = (const float*)d_in[5];
  const float* lq2  = (const float*)d_in[6];
  const float* lk1  = (const float*)d_in[7];
  const float* lk2  = (const float*)d_in[8];
  const float* subw = (const float*)d_in[9];
  const float* wo   = (const float*)d_in[10];
  float* out = (float*)d_out;

  char* ws = (char*)d_ws;
  const size_t SZ = (size_t)2048 * 2048 * 2;  // 8 MB (bf16 2048x2048)
  unsigned short* qraw = (unsigned short*)(ws);
  unsigned short* kraw = (unsigned short*)(ws + SZ);
  unsigned short* vraw = (unsigned short*)(ws + 2 * SZ);
  unsigned short* qatt = (unsigned short*)(ws + 3 * SZ);
  unsigned short* katt = (unsigned short*)(ws + 4 * SZ);
  float* lamb          = (float*)(ws + 5 * SZ);
  unsigned short* aout = qraw;  // qraw is dead after rope(q)

  // LAMBDA_INIT = 0.8 - 0.6*exp(-0.3*12)
  lambda_kernel<<<1, 64, 0, stream>>>(lq1, lq2, lk1, lk2, lamb, 0.7836057665316245f);

  dim3 gg(16, 16);
  gemm_bt<float, float, unsigned short><<<gg, 256, 0, stream>>>(x, wq, qraw, 2048, 2048, 2048);
  gemm_bt<float, float, unsigned short><<<gg, 256, 0, stream>>>(x, wk, kraw, 2048, 2048, 2048);
  gemm_bt<float, float, unsigned short><<<gg, 256, 0, stream>>>(x, wv, vraw, 2048, 2048, 2048);

  rope_kernel<<<8192, 256, 0, stream>>>(qraw, rel, qatt, 0);
  rope_kernel<<<8192, 256, 0, stream>>>(kraw, rel, katt, 1);

  attn_kernel<<<dim3(64, 16, 2), 256, 0, stream>>>(qatt, katt, vraw, lamb, subw, aout);

  gemm_bt<unsigned short, float, float><<<gg, 256, 0, stream>>>(aout, wo, out, 2048, 2048, 2048);
}

// Round 5
// 868.861 us; speedup vs baseline: 2.4598x; 2.4463x over previous
//
#include <hip/hip_runtime.h>

typedef __bf16 bf16x8 __attribute__((ext_vector_type(8)));
typedef float f32x4 __attribute__((ext_vector_type(4)));

__device__ __forceinline__ float bf2f(unsigned short u) {
  return __uint_as_float(((unsigned)u) << 16);
}
__device__ __forceinline__ unsigned short f2bf(float f) {
  unsigned u = __float_as_uint(f);
  return (unsigned short)((u + 0x7fffu + ((u >> 16) & 1u)) >> 16);
}
__device__ __forceinline__ unsigned pack2(float a, float b) {
  return (unsigned)f2bf(a) | ((unsigned)f2bf(b) << 16);
}

// ---------------- lambda scalar ----------------
__global__ void lambda_kernel(const float* __restrict__ lq1, const float* __restrict__ lq2,
                              const float* __restrict__ lk1, const float* __restrict__ lk2,
                              float* __restrict__ out, float lam_init) {
  int l = threadIdx.x;
  float p1 = lq1[l] * lk1[l];
  float p2 = lq2[l] * lk2[l];
  #pragma unroll
  for (int off = 32; off; off >>= 1) {
    p1 += __shfl_xor(p1, off);
    p2 += __shfl_xor(p2, off);
  }
  if (l == 0) out[0] = expf(p1) - expf(p2) + lam_init;
}

// ---------------- GEMM: C[m][n] = sum_k A[m][k] * Bw[n][k] ----------------
// bf16 MFMA 16x16x32; 128x128 tile, BK=32, 4 waves (2x2), 4x4 frags/wave.
template <typename T>
__device__ __forceinline__ void stage16(const T* __restrict__ g, unsigned short* l) {
  if constexpr (sizeof(T) == 4) {
    #pragma unroll
    for (int p = 0; p < 4; ++p) {
      float4 v = reinterpret_cast<const float4*>(g)[p];
      uint2 pk;
      pk.x = pack2(v.x, v.y);
      pk.y = pack2(v.z, v.w);
      *reinterpret_cast<uint2*>(l + p * 4) = pk;
    }
  } else {
    const uint4* s = reinterpret_cast<const uint4*>(g);
    uint4 a = s[0], b = s[1];
    *reinterpret_cast<uint4*>(l) = a;
    *reinterpret_cast<uint4*>(l + 8) = b;
  }
}

template <typename AT, typename BT, typename OT>
__global__ __launch_bounds__(256)
void gemm_bt(const AT* __restrict__ A, const BT* __restrict__ Bw, OT* __restrict__ C,
             int M, int N, int K) {
  __shared__ __align__(16) unsigned short As[128 * 32];
  __shared__ __align__(16) unsigned short Bs[128 * 32];
  const int tid = threadIdx.x;
  const int bm = blockIdx.x * 128, bn = blockIdx.y * 128;
  const int lane = tid & 63, wave = tid >> 6;
  const int wm = (wave >> 1) * 64, wn = (wave & 1) * 64;
  const int srow = tid >> 1, shalf = (tid & 1) * 16;
  const int kf = (lane >> 4) * 8, rr = lane & 15;
  f32x4 acc[4][4] = {};
  for (int kt = 0; kt < K; kt += 32) {
    __syncthreads();
    stage16(&A[(long)(bm + srow) * K + kt + shalf], &As[srow * 32 + shalf]);
    stage16(&Bw[(long)(bn + srow) * K + kt + shalf], &Bs[srow * 32 + shalf]);
    __syncthreads();
    bf16x8 af[4], bq[4];
    #pragma unroll
    for (int i = 0; i < 4; ++i)
      af[i] = *reinterpret_cast<const bf16x8*>(&As[(wm + i * 16 + rr) * 32 + kf]);
    #pragma unroll
    for (int j = 0; j < 4; ++j)
      bq[j] = *reinterpret_cast<const bf16x8*>(&Bs[(wn + j * 16 + rr) * 32 + kf]);
    #pragma unroll
    for (int i = 0; i < 4; ++i)
      #pragma unroll
      for (int j = 0; j < 4; ++j)
        acc[i][j] = __builtin_amdgcn_mfma_f32_16x16x32_bf16(af[i], bq[j], acc[i][j], 0, 0, 0);
  }
  const int r0 = (lane >> 4) * 4, c0 = lane & 15;
  #pragma unroll
  for (int i = 0; i < 4; ++i)
    #pragma unroll
    for (int j = 0; j < 4; ++j) {
      #pragma unroll
      for (int r = 0; r < 4; ++r) {
        long row = bm + wm + i * 16 + r0 + r;
        long col = bn + wn + j * 16 + c0;
        float v = acc[i][j][r];
        if constexpr (sizeof(OT) == 2) C[row * N + col] = f2bf(v);
        else                           C[row * N + col] = v;
      }
    }
}

// ---------------- RoPE (+optional rel_pos pre-scale), with transpose ----------------
// in : raw proj bf16 [(b*1024+t)*2048 + hp*64 + d]   (b,t,hp,d)
// out: bf16 [((b*32+hp)*1024+t)*64 + d]              (b,hp,t,d)
__global__ __launch_bounds__(256) void rope_kernel(const unsigned short* __restrict__ raw,
                                                   const float* __restrict__ rel,
                                                   unsigned short* __restrict__ out,
                                                   int use_rel) {
  int idx = blockIdx.x * 256 + threadIdx.x;  // 2^21 total
  int i = idx & 31;
  int t = (idx >> 5) & 1023;
  int hp = (idx >> 15) & 31;
  int b = idx >> 20;
  int src = (b * 1024 + t) * 2048 + hp * 64 + 2 * i;
  unsigned pair = *reinterpret_cast<const unsigned*>(&raw[src]);
  float x1 = __uint_as_float(pair << 16);
  float x2 = __uint_as_float(pair & 0xffff0000u);
  if (use_rel) {
    x1 *= rel[t * 64 + 2 * i];
    x2 *= rel[t * 64 + 2 * i + 1];
  }
  float inv = expf(-0.28782313662425574f * (float)i);  // 10000^(-2i/64)
  float ang = (float)t * inv;
  float s, c;
  sincosf(ang, &s, &c);
  float r1 = x1 * c - x2 * s;
  float r2 = x1 * s + x2 * c;
  int dst = ((b * 32 + hp) * 1024 + t) * 64 + 2 * i;
  *reinterpret_cast<unsigned*>(&out[dst]) = pack2(r1, r2);
}

// ---------------- differential flash attention + fused sub-LN ----------------
// LDS padding (bank = dword%32 analysis, Guideline 4):
//   Ks [66] shorts/row: 33 dwords/row -> score-phase ds_read_b64 is 2-way (free); was 16-way.
//   Qs [68] floats/row: 68%32=4 -> banks 4*sq+d distinct -> conflict-free; was 4-way.
//   S  [67] floats/row: 67%32=3 -> score writes 2-way (free), PV reads broadcast; was 8-way.
//   Vs [128] unchanged: already 2-way (free) both phases.
#define QB 16
#define KB 64
__global__ __launch_bounds__(256) void attn_kernel(
    const unsigned short* __restrict__ Qa,  // (B,32,T,64) bf16
    const unsigned short* __restrict__ Ka,  // (B,32,T,64) bf16
    const unsigned short* __restrict__ Vr,  // (B,T,2048) bf16 raw-proj layout
    const float* __restrict__ lam_p,
    const float* __restrict__ subln,        // 128
    unsigned short* __restrict__ O) {       // (B,T,2048) bf16
  const int qt = blockIdx.x, h = blockIdx.y, b = blockIdx.z;
  const int tid = threadIdx.x;
  __shared__ __align__(16) float Qs[2][QB][68];
  __shared__ __align__(16) unsigned short Ks[2][KB][66];
  __shared__ __align__(16) unsigned short Vs[KB][128];
  __shared__ float S[2][QB][67];
  __shared__ float mrow[2][QB], lrow[2][QB], rrow[2][QB];

  const float lam = lam_p[0];
  const int q0 = qt * QB;

  // load Q tiles (both sub-heads), pre-scaled by 1/sqrt(D)=1/8
  for (int e = tid; e < 2 * QB * 64; e += 256) {
    int hh = e >> 10;
    int qq = (e >> 6) & 15;
    int d = e & 63;
    float v = bf2f(Qa[((long)(b * 32 + 2 * h + hh) * 1024 + q0 + qq) * 64 + d]);
    Qs[hh][qq][d] = v * 0.125f;
  }
  if (tid < 2 * QB) {
    mrow[tid >> 4][tid & 15] = -1e30f;
    lrow[tid >> 4][tid & 15] = 0.f;
  }

  float o1[8], o2[8];
  #pragma unroll
  for (int j = 0; j < 8; ++j) { o1[j] = 0.f; o2[j] = 0.f; }
  const int oq = tid >> 4, oc = (tid & 15) * 8;

  const int ntiles = (q0 + QB - 1) / KB + 1;
  for (int tile = 0; tile < ntiles; ++tile) {
    const int k0 = tile * KB;
    __syncthreads();  // protect LDS from previous iteration's readers
    // stage K (2 heads x 64 x 64) as uint2
    for (int e = tid; e < 2 * KB * 16; e += 256) {
      int hh = e >> 10;
      int kk = (e >> 4) & 63;
      int dq = (e & 15) * 4;
      *reinterpret_cast<uint2*>(&Ks[hh][kk][dq]) = *reinterpret_cast<const uint2*>(
          &Ka[((long)(b * 32 + 2 * h + hh) * 1024 + k0 + kk) * 64 + dq]);
    }
    // stage V (64 x 128)
    for (int e = tid; e < KB * 32; e += 256) {
      int kk = e >> 5;
      int cq = (e & 31) * 4;
      *reinterpret_cast<uint2*>(&Vs[kk][cq]) = *reinterpret_cast<const uint2*>(
          &Vr[(long)(b * 1024 + k0 + kk) * 2048 + h * 128 + cq]);
    }
    __syncthreads();
    // scores: thread -> (sq, 4 consecutive ks), both heads
    {
      const int sq = tid >> 4;
      const int sk = (tid & 15) * 4;
      const int qglob = q0 + sq;
      float sa[4] = {0.f, 0.f, 0.f, 0.f}, sb[4] = {0.f, 0.f, 0.f, 0.f};
      for (int d = 0; d < 64; d += 4) {
        float4 qa = *reinterpret_cast<const float4*>(&Qs[0][sq][d]);
        float4 qb = *reinterpret_cast<const float4*>(&Qs[1][sq][d]);
        #pragma unroll
        for (int kk = 0; kk < 4; ++kk) {
          uint2 ka = *reinterpret_cast<const uint2*>(&Ks[0][sk + kk][d]);
          uint2 kb = *reinterpret_cast<const uint2*>(&Ks[1][sk + kk][d]);
          sa[kk] += qa.x * __uint_as_float(ka.x << 16) + qa.y * __uint_as_float(ka.x & 0xffff0000u) +
                    qa.z * __uint_as_float(ka.y << 16) + qa.w * __uint_as_float(ka.y & 0xffff0000u);
          sb[kk] += qb.x * __uint_as_float(kb.x << 16) + qb.y * __uint_as_float(kb.x & 0xffff0000u) +
                    qb.z * __uint_as_float(kb.y << 16) + qb.w * __uint_as_float(kb.y & 0xffff0000u);
        }
      }
      #pragma unroll
      for (int kk = 0; kk < 4; ++kk) {
        bool msk = (k0 + sk + kk) > qglob;
        S[0][sq][sk + kk] = msk ? -1e30f : sa[kk];
        S[1][sq][sk + kk] = msk ? -1e30f : sb[kk];
      }
    }
    __syncthreads();
    // online softmax per row: 32 rows, 8 threads each
    {
      const int row = tid >> 3, sub = tid & 7;
      const int hh = row >> 4, qq = row & 15;
      float mx = -1e30f;
      for (int kk = sub; kk < KB; kk += 8) mx = fmaxf(mx, S[hh][qq][kk]);
      #pragma unroll
      for (int off = 4; off; off >>= 1) mx = fmaxf(mx, __shfl_xor(mx, off));
      float mold = mrow[hh][qq];
      float mnew = fmaxf(mold, mx);
      float ls = 0.f;
      for (int kk = sub; kk < KB; kk += 8) {
        float p = __expf(S[hh][qq][kk] - mnew);  // masked: exp(-1e30-m) == 0
        S[hh][qq][kk] = p;
        ls += p;
      }
      #pragma unroll
      for (int off = 4; off; off >>= 1) ls += __shfl_xor(ls, off);
      if (sub == 0) {
        float resc = __expf(mold - mnew);
        lrow[hh][qq] = lrow[hh][qq] * resc + ls;
        mrow[hh][qq] = mnew;
        rrow[hh][qq] = resc;
      }
    }
    __syncthreads();
    // PV accumulate: thread -> (oq, 8 channels)
    {
      float rA = rrow[0][oq], rB = rrow[1][oq];
      #pragma unroll
      for (int j = 0; j < 8; ++j) { o1[j] *= rA; o2[j] *= rB; }
      for (int kk = 0; kk < KB; ++kk) {
        float pA = S[0][oq][kk], pB = S[1][oq][kk];
        uint4 vv = *reinterpret_cast<const uint4*>(&Vs[kk][oc]);
        float vf[8];
        vf[0] = __uint_as_float(vv.x << 16); vf[1] = __uint_as_float(vv.x & 0xffff0000u);
        vf[2] = __uint_as_float(vv.y << 16); vf[3] = __uint_as_float(vv.y & 0xffff0000u);
        vf[4] = __uint_as_float(vv.z << 16); vf[5] = __uint_as_float(vv.z & 0xffff0000u);
        vf[6] = __uint_as_float(vv.w << 16); vf[7] = __uint_as_float(vv.w & 0xffff0000u);
        #pragma unroll
        for (int j = 0; j < 8; ++j) { o1[j] += pA * vf[j]; o2[j] += pB * vf[j]; }
      }
    }
  }
  // epilogue: combine, RMS-norm over 128, subln scale, store bf16
  float lA = lrow[0][oq], lB = lrow[1][oq];
  float iA = 1.f / lA, iB = lam / lB;
  float at[8], ss = 0.f;
  #pragma unroll
  for (int j = 0; j < 8; ++j) {
    at[j] = o1[j] * iA - o2[j] * iB;
    ss += at[j] * at[j];
  }
  #pragma unroll
  for (int off = 8; off; off >>= 1) ss += __shfl_xor(ss, off);
  float scale = rsqrtf(ss * (1.f / 128.f) + 1e-5f);
  float vj[8];
  #pragma unroll
  for (int j = 0; j < 8; ++j) vj[j] = at[j] * scale * subln[oc + j];
  uint4 ow;
  ow.x = pack2(vj[0], vj[1]);
  ow.y = pack2(vj[2], vj[3]);
  ow.z = pack2(vj[4], vj[5]);
  ow.w = pack2(vj[6], vj[7]);
  const int qglob = q0 + oq;
  *reinterpret_cast<uint4*>(&O[(long)(b * 1024 + qglob) * 2048 + h * 128 + oc]) = ow;
}

extern "C" void kernel_launch(void* const* d_in, const int* in_sizes, int n_in,
                              void* d_out, int out_size, void* d_ws, size_t ws_size,
                              hipStream_t stream) {
  (void)in_sizes; (void)n_in; (void)out_size; (void)ws_size;
  const float* x    = (const float*)d_in[0];
  const float* rel  = (const float*)d_in[1];
  const float* wq   = (const float*)d_in[2];
  const float* wk   = (const float*)d_in[3];
  const float* wv   = (const float*)d_in[4];
  const float* lq1  = (const float*)d_in[5];
  const float* lq2  = (const float*)d_in[6];
  const float* lk1  = (const float*)d_in[7];
  const float* lk2  = (const float*)d_in[8];
  const float* subw = (const float*)d_in[9];
  const float* wo   = (const float*)d_in[10];
  float* out = (float*)d_out;

  char* ws = (char*)d_ws;
  const size_t SZ = (size_t)2048 * 2048 * 2;  // 8 MB (bf16 2048x2048)
  unsigned short* qraw = (unsigned short*)(ws);
  unsigned short* kraw = (unsigned short*)(ws + SZ);
  unsigned short* vraw = (unsigned short*)(ws + 2 * SZ);
  unsigned short* qatt = (unsigned short*)(ws + 3 * SZ);
  unsigned short* katt = (unsigned short*)(ws + 4 * SZ);
  float* lamb          = (float*)(ws + 5 * SZ);
  unsigned short* aout = qraw;  // qraw is dead after rope(q)

  // LAMBDA_INIT = 0.8 - 0.6*exp(-0.3*12)
  lambda_kernel<<<1, 64, 0, stream>>>(lq1, lq2, lk1, lk2, lamb, 0.7836057665316245f);

  dim3 gg(16, 16);
  gemm_bt<float, float, unsigned short><<<gg, 256, 0, stream>>>(x, wq, qraw, 2048, 2048, 2048);
  gemm_bt<float, float, unsigned short><<<gg, 256, 0, stream>>>(x, wk, kraw, 2048, 2048, 2048);
  gemm_bt<float, float, unsigned short><<<gg, 256, 0, stream>>>(x, wv, vraw, 2048, 2048, 2048);

  rope_kernel<<<8192, 256, 0, stream>>>(qraw, rel, qatt, 0);
  rope_kernel<<<8192, 256, 0, stream>>>(kraw, rel, katt, 1);

  attn_kernel<<<dim3(64, 16, 2), 256, 0, stream>>>(qatt, katt, vraw, lamb, subw, aout);

  gemm_bt<unsigned short, float, float><<<gg, 256, 0, stream>>>(aout, wo, out, 2048, 2048, 2048);
}

// Round 6
// 591.482 us; speedup vs baseline: 3.6133x; 1.4690x over previous
//
#include <hip/hip_runtime.h>

typedef __bf16 bf16x8 __attribute__((ext_vector_type(8)));
typedef float f32x4 __attribute__((ext_vector_type(4)));

__device__ __forceinline__ float bf2f(unsigned short u) {
  return __uint_as_float(((unsigned)u) << 16);
}
__device__ __forceinline__ unsigned short f2bf(float f) {
  unsigned u = __float_as_uint(f);
  return (unsigned short)((u + 0x7fffu + ((u >> 16) & 1u)) >> 16);
}
__device__ __forceinline__ unsigned pack2(float a, float b) {
  return (unsigned)f2bf(a) | ((unsigned)f2bf(b) << 16);
}

// XOR swizzle on 16B blocks within a 128B row (T2 / Guideline 4).
#define SWZB(row, byte) ((byte) ^ (((row) & 7) << 4))

// ---------------- lambda scalar ----------------
__global__ void lambda_kernel(const float* __restrict__ lq1, const float* __restrict__ lq2,
                              const float* __restrict__ lk1, const float* __restrict__ lk2,
                              float* __restrict__ out, float lam_init) {
  int l = threadIdx.x;
  float p1 = lq1[l] * lk1[l];
  float p2 = lq2[l] * lk2[l];
  #pragma unroll
  for (int off = 32; off; off >>= 1) {
    p1 += __shfl_xor(p1, off);
    p2 += __shfl_xor(p2, off);
  }
  if (l == 0) out[0] = expf(p1) - expf(p2) + lam_init;
}

// ---------------- GEMM: C[m][n] = sum_k A[m][k] * Bw[n][k] ----------------
template <typename T>
__device__ __forceinline__ void stage16(const T* __restrict__ g, unsigned short* l) {
  if constexpr (sizeof(T) == 4) {
    #pragma unroll
    for (int p = 0; p < 4; ++p) {
      float4 v = reinterpret_cast<const float4*>(g)[p];
      uint2 pk;
      pk.x = pack2(v.x, v.y);
      pk.y = pack2(v.z, v.w);
      *reinterpret_cast<uint2*>(l + p * 4) = pk;
    }
  } else {
    const uint4* s = reinterpret_cast<const uint4*>(g);
    uint4 a = s[0], b = s[1];
    *reinterpret_cast<uint4*>(l) = a;
    *reinterpret_cast<uint4*>(l + 8) = b;
  }
}

template <typename AT, typename BT, typename OT>
__global__ __launch_bounds__(256)
void gemm_bt(const AT* __restrict__ A, const BT* __restrict__ Bw, OT* __restrict__ C,
             int M, int N, int K) {
  __shared__ __align__(16) unsigned short As[128 * 32];
  __shared__ __align__(16) unsigned short Bs[128 * 32];
  const int tid = threadIdx.x;
  const int bm = blockIdx.x * 128, bn = blockIdx.y * 128;
  const int lane = tid & 63, wave = tid >> 6;
  const int wm = (wave >> 1) * 64, wn = (wave & 1) * 64;
  const int srow = tid >> 1, shalf = (tid & 1) * 16;
  const int kf = (lane >> 4) * 8, rr = lane & 15;
  f32x4 acc[4][4] = {};
  for (int kt = 0; kt < K; kt += 32) {
    __syncthreads();
    stage16(&A[(long)(bm + srow) * K + kt + shalf], &As[srow * 32 + shalf]);
    stage16(&Bw[(long)(bn + srow) * K + kt + shalf], &Bs[srow * 32 + shalf]);
    __syncthreads();
    bf16x8 af[4], bq[4];
    #pragma unroll
    for (int i = 0; i < 4; ++i)
      af[i] = *reinterpret_cast<const bf16x8*>(&As[(wm + i * 16 + rr) * 32 + kf]);
    #pragma unroll
    for (int j = 0; j < 4; ++j)
      bq[j] = *reinterpret_cast<const bf16x8*>(&Bs[(wn + j * 16 + rr) * 32 + kf]);
    #pragma unroll
    for (int i = 0; i < 4; ++i)
      #pragma unroll
      for (int j = 0; j < 4; ++j)
        acc[i][j] = __builtin_amdgcn_mfma_f32_16x16x32_bf16(af[i], bq[j], acc[i][j], 0, 0, 0);
  }
  const int r0 = (lane >> 4) * 4, c0 = lane & 15;
  #pragma unroll
  for (int i = 0; i < 4; ++i)
    #pragma unroll
    for (int j = 0; j < 4; ++j) {
      #pragma unroll
      for (int r = 0; r < 4; ++r) {
        long row = bm + wm + i * 16 + r0 + r;
        long col = bn + wn + j * 16 + c0;
        float v = acc[i][j][r];
        if constexpr (sizeof(OT) == 2) C[row * N + col] = f2bf(v);
        else                           C[row * N + col] = v;
      }
    }
}

// ---------------- RoPE (+optional rel_pos pre-scale), with transpose ----------------
__global__ __launch_bounds__(256) void rope_kernel(const unsigned short* __restrict__ raw,
                                                   const float* __restrict__ rel,
                                                   unsigned short* __restrict__ out,
                                                   int use_rel) {
  int idx = blockIdx.x * 256 + threadIdx.x;  // 2^21 total
  int i = idx & 31;
  int t = (idx >> 5) & 1023;
  int hp = (idx >> 15) & 31;
  int b = idx >> 20;
  int src = (b * 1024 + t) * 2048 + hp * 64 + 2 * i;
  unsigned pair = *reinterpret_cast<const unsigned*>(&raw[src]);
  float x1 = __uint_as_float(pair << 16);
  float x2 = __uint_as_float(pair & 0xffff0000u);
  if (use_rel) {
    x1 *= rel[t * 64 + 2 * i];
    x2 *= rel[t * 64 + 2 * i + 1];
  }
  float inv = expf(-0.28782313662425574f * (float)i);  // 10000^(-2i/64)
  float ang = (float)t * inv;
  float s, c;
  sincosf(ang, &s, &c);
  float r1 = x1 * c - x2 * s;
  float r2 = x1 * s + x2 * c;
  int dst = ((b * 32 + hp) * 1024 + t) * 64 + 2 * i;
  *reinterpret_cast<unsigned*>(&out[dst]) = pack2(r1, r2);
}

// ---------------- V transpose: (b, t, 2048) -> (b, n, 1024) ----------------
__global__ __launch_bounds__(256) void transpose_v(const unsigned short* __restrict__ in,
                                                   unsigned short* __restrict__ out) {
  __shared__ unsigned short ls[64][68];
  const int t0 = blockIdx.x * 64, n0 = blockIdx.y * 64, b = blockIdx.z;
  const int tid = threadIdx.x;
  #pragma unroll
  for (int p = 0; p < 4; ++p) {
    int idx = p * 256 + tid;
    int tl = idx >> 4, nq = (idx & 15) * 4;
    *reinterpret_cast<uint2*>(&ls[tl][nq]) = *reinterpret_cast<const uint2*>(
        &in[((long)(b * 1024 + t0 + tl)) * 2048 + n0 + nq]);
  }
  __syncthreads();
  #pragma unroll
  for (int p = 0; p < 4; ++p) {
    int idx = p * 256 + tid;
    int nl = idx >> 4, tq = (idx & 15) * 4;
    unsigned short a0 = ls[tq + 0][nl], a1 = ls[tq + 1][nl];
    unsigned short a2 = ls[tq + 2][nl], a3 = ls[tq + 3][nl];
    uint2 o;
    o.x = (unsigned)a0 | ((unsigned)a1 << 16);
    o.y = (unsigned)a2 | ((unsigned)a3 << 16);
    *reinterpret_cast<uint2*>(&out[((long)(b * 2048 + n0 + nl)) * 1024 + t0 + tq]) = o;
  }
}

// ---------------- MFMA differential flash attention + fused sub-LN ----------------
// 4 waves; wave w owns q rows q0 + w*16 .. +15. KB=64.
// Frag layouts identical to gemm_bt (verified): A row = lane&15, kf = (lane>>4)*8;
// C row = (lane>>4)*4 + r, col = lane&15. Softmax stats per-lane (shfl over col group).
__global__ __launch_bounds__(256) void attn_mfma(
    const unsigned short* __restrict__ Qa,   // (B,32,T,64) bf16
    const unsigned short* __restrict__ Ka,   // (B,32,T,64) bf16
    const unsigned short* __restrict__ Vt,   // (B,2048,T) bf16 (V transposed)
    const float* __restrict__ lam_p,
    const float* __restrict__ subln,         // 128
    unsigned short* __restrict__ O) {        // (B,T,2048) bf16
  const int qt = blockIdx.x, h = blockIdx.y, b = blockIdx.z;
  const int tid = threadIdx.x;
  const int lane = tid & 63, w = tid >> 6;
  const int lg = lane >> 4, cc = lane & 15;
  const int q0 = qt * 64;

  __shared__ __align__(16) unsigned short KsBuf[2 * 64 * 64];  // [hh][k][d], swizzled rows
  __shared__ __align__(16) unsigned short VsBuf[128 * 64];     // [c][k], swizzled rows
  __shared__ __align__(16) unsigned short PbBuf[2 * 64 * 64];  // [hh][q][k] bf16, swizzled rows

  const float lam = lam_p[0];

  // Q fragments in registers for the whole kernel (row = lane&15 of wave's block).
  bf16x8 qf[2][2];
  {
    const long qrow = q0 + w * 16 + cc;
    #pragma unroll
    for (int hh = 0; hh < 2; ++hh)
      #pragma unroll
      for (int c = 0; c < 2; ++c)
        qf[hh][c] = *reinterpret_cast<const bf16x8*>(
            &Qa[((long)((b * 32 + 2 * h + hh) * 1024) + qrow) * 64 + c * 32 + lg * 8]);
  }
  float sl[8];
  #pragma unroll
  for (int jc = 0; jc < 8; ++jc) sl[jc] = subln[jc * 16 + cc];

  f32x4 acc_o[2][8];
  float mS[2][4], lS[2][4];
  #pragma unroll
  for (int hh = 0; hh < 2; ++hh) {
    #pragma unroll
    for (int jc = 0; jc < 8; ++jc) acc_o[hh][jc] = (f32x4){0.f, 0.f, 0.f, 0.f};
    #pragma unroll
    for (int r = 0; r < 4; ++r) { mS[hh][r] = -1e30f; lS[hh][r] = 0.f; }
  }

  char* ksb = reinterpret_cast<char*>(KsBuf);
  char* vsb = reinterpret_cast<char*>(VsBuf);
  char* pbb = reinterpret_cast<char*>(PbBuf);

  const int nt = qt + 1;
  for (int tile = 0; tile < nt; ++tile) {
    const int k0 = tile * 64;
    __syncthreads();
    // stage K: 2 sub-heads x 64 rows x 64 d (uint2 per thread-slot)
    #pragma unroll
    for (int p = 0; p < 8; ++p) {
      int idx = p * 256 + tid;  // 0..2047
      int hh = idx >> 10;
      int kk = (idx >> 4) & 63;
      int dq = idx & 15;
      uint2 vld = *reinterpret_cast<const uint2*>(
          &Ka[((long)((b * 32 + 2 * h + hh) * 1024) + k0 + kk) * 64 + dq * 4]);
      *reinterpret_cast<uint2*>(ksb + hh * 8192 + kk * 128 + SWZB(kk, dq * 8)) = vld;
    }
    // stage V^T tile: 128 channel-rows x 64 k
    #pragma unroll
    for (int p = 0; p < 8; ++p) {
      int idx = p * 256 + tid;  // 0..2047
      int cr = idx >> 4;        // 0..127
      int kq = idx & 15;
      uint2 vld = *reinterpret_cast<const uint2*>(
          &Vt[((long)(b * 2048 + h * 128 + cr)) * 1024 + k0 + kq * 4]);
      *reinterpret_cast<uint2*>(vsb + cr * 128 + SWZB(cr, kq * 8)) = vld;
    }
    __syncthreads();

    // ---- QK^T + online softmax + P->bf16 LDS ----
    float rescv[2][4];
    #pragma unroll
    for (int hh = 0; hh < 2; ++hh) {
      f32x4 s4[4];
      #pragma unroll
      for (int j = 0; j < 4; ++j) s4[j] = (f32x4){0.f, 0.f, 0.f, 0.f};
      #pragma unroll
      for (int j = 0; j < 4; ++j) {
        int row = j * 16 + cc;
        const char* base = ksb + hh * 8192 + row * 128;
        bf16x8 kb0 = *reinterpret_cast<const bf16x8*>(base + SWZB(row, lg * 16));
        bf16x8 kb1 = *reinterpret_cast<const bf16x8*>(base + SWZB(row, lg * 16 + 64));
        s4[j] = __builtin_amdgcn_mfma_f32_16x16x32_bf16(qf[hh][0], kb0, s4[j], 0, 0, 0);
        s4[j] = __builtin_amdgcn_mfma_f32_16x16x32_bf16(qf[hh][1], kb1, s4[j], 0, 0, 0);
      }
      // scale + causal mask
      #pragma unroll
      for (int j = 0; j < 4; ++j) {
        int kcol = k0 + j * 16 + cc;
        #pragma unroll
        for (int r = 0; r < 4; ++r) {
          int qrow = q0 + w * 16 + lg * 4 + r;
          float s = s4[j][r] * 0.125f;
          s4[j][r] = (kcol > qrow) ? -1e30f : s;
        }
      }
      // per-row online softmax (row-reduce over the 16-lane col group)
      #pragma unroll
      for (int r = 0; r < 4; ++r) {
        float mx = fmaxf(fmaxf(s4[0][r], s4[1][r]), fmaxf(s4[2][r], s4[3][r]));
        mx = fmaxf(mx, __shfl_xor(mx, 1));
        mx = fmaxf(mx, __shfl_xor(mx, 2));
        mx = fmaxf(mx, __shfl_xor(mx, 4));
        mx = fmaxf(mx, __shfl_xor(mx, 8));
        float mold = mS[hh][r];
        float mnew = fmaxf(mold, mx);
        mS[hh][r] = mnew;
        float rsc = __expf(mold - mnew);
        rescv[hh][r] = rsc;
        float ls = 0.f;
        #pragma unroll
        for (int j = 0; j < 4; ++j) {
          float p = __expf(s4[j][r] - mnew);  // masked -> exp(-1e30-m) == 0
          s4[j][r] = p;
          ls += p;
        }
        ls += __shfl_xor(ls, 1);
        ls += __shfl_xor(ls, 2);
        ls += __shfl_xor(ls, 4);
        ls += __shfl_xor(ls, 8);
        lS[hh][r] = lS[hh][r] * rsc + ls;
      }
      // write P (bf16) in A-frag-compatible swizzled rows
      #pragma unroll
      for (int j = 0; j < 4; ++j)
        #pragma unroll
        for (int r = 0; r < 4; ++r) {
          int qrl = w * 16 + lg * 4 + r;
          *reinterpret_cast<unsigned short*>(
              pbb + (hh * 64 + qrl) * 128 + SWZB(qrl, (j * 16 + cc) * 2)) = f2bf(s4[j][r]);
        }
    }
    __syncthreads();

    // ---- PV ----
    bf16x8 pa[2][2];
    {
      int qrl = w * 16 + cc;
      #pragma unroll
      for (int hh = 0; hh < 2; ++hh)
        #pragma unroll
        for (int c = 0; c < 2; ++c)
          pa[hh][c] = *reinterpret_cast<const bf16x8*>(
              pbb + (hh * 64 + qrl) * 128 + SWZB(qrl, lg * 16 + c * 64));
    }
    #pragma unroll
    for (int hh = 0; hh < 2; ++hh)
      #pragma unroll
      for (int jc = 0; jc < 8; ++jc)
        #pragma unroll
        for (int r = 0; r < 4; ++r)
          acc_o[hh][jc][r] *= rescv[hh][r];
    #pragma unroll
    for (int jc = 0; jc < 8; ++jc) {
      int row = jc * 16 + cc;
      const char* base = vsb + row * 128;
      bf16x8 vf0 = *reinterpret_cast<const bf16x8*>(base + SWZB(row, lg * 16));
      bf16x8 vf1 = *reinterpret_cast<const bf16x8*>(base + SWZB(row, lg * 16 + 64));
      #pragma unroll
      for (int hh = 0; hh < 2; ++hh) {
        acc_o[hh][jc] = __builtin_amdgcn_mfma_f32_16x16x32_bf16(pa[hh][0], vf0, acc_o[hh][jc], 0, 0, 0);
        acc_o[hh][jc] = __builtin_amdgcn_mfma_f32_16x16x32_bf16(pa[hh][1], vf1, acc_o[hh][jc], 0, 0, 0);
      }
    }
  }

  // ---- epilogue: diff-combine, RMS over 128, subln, store bf16 ----
  float sc[4];
  #pragma unroll
  for (int r = 0; r < 4; ++r) {
    float inv1 = 1.f / lS[0][r];
    float inv2 = lam / lS[1][r];
    float ss = 0.f;
    #pragma unroll
    for (int jc = 0; jc < 8; ++jc) {
      float at = acc_o[0][jc][r] * inv1 - acc_o[1][jc][r] * inv2;
      acc_o[0][jc][r] = at;
      ss += at * at;
    }
    ss += __shfl_xor(ss, 1);
    ss += __shfl_xor(ss, 2);
    ss += __shfl_xor(ss, 4);
    ss += __shfl_xor(ss, 8);
    sc[r] = rsqrtf(ss * (1.f / 128.f) + 1e-5f);
  }
  #pragma unroll
  for (int r = 0; r < 4; ++r) {
    long qrow = q0 + w * 16 + lg * 4 + r;
    #pragma unroll
    for (int jc = 0; jc < 8; ++jc) {
      O[(long)(b * 1024 + qrow) * 2048 + h * 128 + jc * 16 + cc] =
          f2bf(acc_o[0][jc][r] * sc[r] * sl[jc]);
    }
  }
}

extern "C" void kernel_launch(void* const* d_in, const int* in_sizes, int n_in,
                              void* d_out, int out_size, void* d_ws, size_t ws_size,
                              hipStream_t stream) {
  (void)in_sizes; (void)n_in; (void)out_size; (void)ws_size;
  const float* x    = (const float*)d_in[0];
  const float* rel  = (const float*)d_in[1];
  const float* wq   = (const float*)d_in[2];
  const float* wk   = (const float*)d_in[3];
  const float* wv   = (const float*)d_in[4];
  const float* lq1  = (const float*)d_in[5];
  const float* lq2  = (const float*)d_in[6];
  const float* lk1  = (const float*)d_in[7];
  const float* lk2  = (const float*)d_in[8];
  const float* subw = (const float*)d_in[9];
  const float* wo   = (const float*)d_in[10];
  float* out = (float*)d_out;

  char* ws = (char*)d_ws;
  const size_t SZ = (size_t)2048 * 2048 * 2;  // 8 MB (bf16 2048x2048)
  unsigned short* qraw = (unsigned short*)(ws);
  unsigned short* kraw = (unsigned short*)(ws + SZ);
  unsigned short* vraw = (unsigned short*)(ws + 2 * SZ);
  unsigned short* qatt = (unsigned short*)(ws + 3 * SZ);
  unsigned short* katt = (unsigned short*)(ws + 4 * SZ);
  float* lamb          = (float*)(ws + 5 * SZ);
  unsigned short* vtb  = kraw;  // kraw dead after rope(k)
  unsigned short* aout = qraw;  // qraw dead after rope(q)

  // LAMBDA_INIT = 0.8 - 0.6*exp(-0.3*12)
  lambda_kernel<<<1, 64, 0, stream>>>(lq1, lq2, lk1, lk2, lamb, 0.7836057665316245f);

  dim3 gg(16, 16);
  gemm_bt<float, float, unsigned short><<<gg, 256, 0, stream>>>(x, wq, qraw, 2048, 2048, 2048);
  gemm_bt<float, float, unsigned short><<<gg, 256, 0, stream>>>(x, wk, kraw, 2048, 2048, 2048);
  gemm_bt<float, float, unsigned short><<<gg, 256, 0, stream>>>(x, wv, vraw, 2048, 2048, 2048);

  rope_kernel<<<8192, 256, 0, stream>>>(qraw, rel, qatt, 0);
  rope_kernel<<<8192, 256, 0, stream>>>(kraw, rel, katt, 1);

  transpose_v<<<dim3(16, 32, 2), 256, 0, stream>>>(vraw, vtb);

  attn_mfma<<<dim3(16, 16, 2), 256, 0, stream>>>(qatt, katt, vtb, lamb, subw, aout);

  gemm_bt<unsigned short, float, float><<<gg, 256, 0, stream>>>(aout, wo, out, 2048, 2048, 2048);
}

// Round 7
// 431.712 us; speedup vs baseline: 4.9505x; 1.3701x over previous
//
#include <hip/hip_runtime.h>

typedef __bf16 bf16x8 __attribute__((ext_vector_type(8)));
typedef float f32x4 __attribute__((ext_vector_type(4)));

__device__ __forceinline__ float bf2f(unsigned short u) {
  return __uint_as_float(((unsigned)u) << 16);
}
__device__ __forceinline__ unsigned short f2bf(float f) {
  unsigned u = __float_as_uint(f);
  return (unsigned short)((u + 0x7fffu + ((u >> 16) & 1u)) >> 16);
}
__device__ __forceinline__ unsigned pack2(float a, float b) {
  return (unsigned)f2bf(a) | ((unsigned)f2bf(b) << 16);
}

// XOR swizzle on 16B blocks within a 128B row (T2 / Guideline 4).
#define SWZB(row, byte) ((byte) ^ (((row) & 7) << 4))

// ---------------- lambda scalar ----------------
__global__ void lambda_kernel(const float* __restrict__ lq1, const float* __restrict__ lq2,
                              const float* __restrict__ lk1, const float* __restrict__ lk2,
                              float* __restrict__ out, float lam_init) {
  int l = threadIdx.x;
  float p1 = lq1[l] * lk1[l];
  float p2 = lq2[l] * lk2[l];
  #pragma unroll
  for (int off = 32; off; off >>= 1) {
    p1 += __shfl_xor(p1, off);
    p2 += __shfl_xor(p2, off);
  }
  if (l == 0) out[0] = expf(p1) - expf(p2) + lam_init;
}

// ---------------- GEMM: C[m][n] = sum_k A[m][k] * Bw[n][k] ----------------
template <typename T>
__device__ __forceinline__ void stage16(const T* __restrict__ g, unsigned short* l) {
  if constexpr (sizeof(T) == 4) {
    #pragma unroll
    for (int p = 0; p < 4; ++p) {
      float4 v = reinterpret_cast<const float4*>(g)[p];
      uint2 pk;
      pk.x = pack2(v.x, v.y);
      pk.y = pack2(v.z, v.w);
      *reinterpret_cast<uint2*>(l + p * 4) = pk;
    }
  } else {
    const uint4* s = reinterpret_cast<const uint4*>(g);
    uint4 a = s[0], b = s[1];
    *reinterpret_cast<uint4*>(l) = a;
    *reinterpret_cast<uint4*>(l + 8) = b;
  }
}

template <typename AT, typename BT, typename OT>
__global__ __launch_bounds__(256)
void gemm_bt(const AT* __restrict__ A, const BT* __restrict__ Bw, OT* __restrict__ C,
             int M, int N, int K) {
  __shared__ __align__(16) unsigned short As[128 * 32];
  __shared__ __align__(16) unsigned short Bs[128 * 32];
  const int tid = threadIdx.x;
  const int bm = blockIdx.x * 128, bn = blockIdx.y * 128;
  const int lane = tid & 63, wave = tid >> 6;
  const int wm = (wave >> 1) * 64, wn = (wave & 1) * 64;
  const int srow = tid >> 1, shalf = (tid & 1) * 16;
  const int kf = (lane >> 4) * 8, rr = lane & 15;
  f32x4 acc[4][4] = {};
  for (int kt = 0; kt < K; kt += 32) {
    __syncthreads();
    stage16(&A[(long)(bm + srow) * K + kt + shalf], &As[srow * 32 + shalf]);
    stage16(&Bw[(long)(bn + srow) * K + kt + shalf], &Bs[srow * 32 + shalf]);
    __syncthreads();
    bf16x8 af[4], bq[4];
    #pragma unroll
    for (int i = 0; i < 4; ++i)
      af[i] = *reinterpret_cast<const bf16x8*>(&As[(wm + i * 16 + rr) * 32 + kf]);
    #pragma unroll
    for (int j = 0; j < 4; ++j)
      bq[j] = *reinterpret_cast<const bf16x8*>(&Bs[(wn + j * 16 + rr) * 32 + kf]);
    #pragma unroll
    for (int i = 0; i < 4; ++i)
      #pragma unroll
      for (int j = 0; j < 4; ++j)
        acc[i][j] = __builtin_amdgcn_mfma_f32_16x16x32_bf16(af[i], bq[j], acc[i][j], 0, 0, 0);
  }
  const int r0 = (lane >> 4) * 4, c0 = lane & 15;
  #pragma unroll
  for (int i = 0; i < 4; ++i)
    #pragma unroll
    for (int j = 0; j < 4; ++j) {
      #pragma unroll
      for (int r = 0; r < 4; ++r) {
        long row = bm + wm + i * 16 + r0 + r;
        long col = bn + wn + j * 16 + c0;
        float v = acc[i][j][r];
        if constexpr (sizeof(OT) == 2) C[row * N + col] = f2bf(v);
        else                           C[row * N + col] = v;
      }
    }
}

// ---------------- RoPE (+optional rel_pos pre-scale), with transpose ----------------
__global__ __launch_bounds__(256) void rope_kernel(const unsigned short* __restrict__ raw,
                                                   const float* __restrict__ rel,
                                                   unsigned short* __restrict__ out,
                                                   int use_rel) {
  int idx = blockIdx.x * 256 + threadIdx.x;  // 2^21 total
  int i = idx & 31;
  int t = (idx >> 5) & 1023;
  int hp = (idx >> 15) & 31;
  int b = idx >> 20;
  int src = (b * 1024 + t) * 2048 + hp * 64 + 2 * i;
  unsigned pair = *reinterpret_cast<const unsigned*>(&raw[src]);
  float x1 = __uint_as_float(pair << 16);
  float x2 = __uint_as_float(pair & 0xffff0000u);
  if (use_rel) {
    x1 *= rel[t * 64 + 2 * i];
    x2 *= rel[t * 64 + 2 * i + 1];
  }
  float inv = expf(-0.28782313662425574f * (float)i);  // 10000^(-2i/64)
  float ang = (float)t * inv;
  float s, c;
  sincosf(ang, &s, &c);
  float r1 = x1 * c - x2 * s;
  float r2 = x1 * s + x2 * c;
  int dst = ((b * 32 + hp) * 1024 + t) * 64 + 2 * i;
  *reinterpret_cast<unsigned*>(&out[dst]) = pack2(r1, r2);
}

// ---------------- V transpose: (b, t, 2048) -> (b, n, 1024) ----------------
__global__ __launch_bounds__(256) void transpose_v(const unsigned short* __restrict__ in,
                                                   unsigned short* __restrict__ out) {
  __shared__ unsigned short ls[64][68];
  const int t0 = blockIdx.x * 64, n0 = blockIdx.y * 64, b = blockIdx.z;
  const int tid = threadIdx.x;
  #pragma unroll
  for (int p = 0; p < 4; ++p) {
    int idx = p * 256 + tid;
    int tl = idx >> 4, nq = (idx & 15) * 4;
    *reinterpret_cast<uint2*>(&ls[tl][nq]) = *reinterpret_cast<const uint2*>(
        &in[((long)(b * 1024 + t0 + tl)) * 2048 + n0 + nq]);
  }
  __syncthreads();
  #pragma unroll
  for (int p = 0; p < 4; ++p) {
    int idx = p * 256 + tid;
    int nl = idx >> 4, tq = (idx & 15) * 4;
    unsigned short a0 = ls[tq + 0][nl], a1 = ls[tq + 1][nl];
    unsigned short a2 = ls[tq + 2][nl], a3 = ls[tq + 3][nl];
    uint2 o;
    o.x = (unsigned)a0 | ((unsigned)a1 << 16);
    o.y = (unsigned)a2 | ((unsigned)a3 << 16);
    *reinterpret_cast<uint2*>(&out[((long)(b * 2048 + n0 + nl)) * 1024 + t0 + tq]) = o;
  }
}

// ---------------- MFMA differential flash attention + fused sub-LN ----------------
// Balanced 2-pass blocks: block bx processes 32-row q-subtiles {bx, 31-bx} -> every
// block does exactly 17 K-tile iterations (causal work sum is constant).
// 4 waves: wave w owns (16 q-rows qoff=(w&1)*16, sub-head hh=w>>1). P is wave-private
// (2KB each) -> only 2 barriers per tile-iter. Epilogue: hh1 waves deposit lam/l2*o2
// into LDS (reusing K buffer, jc^row swizzle), hh0 waves combine + RMS + subln + store.
__global__ __launch_bounds__(256) void attn_mfma(
    const unsigned short* __restrict__ Qa,   // (B,32,T,64) bf16
    const unsigned short* __restrict__ Ka,   // (B,32,T,64) bf16
    const unsigned short* __restrict__ Vt,   // (B,2048,T) bf16 (V transposed)
    const float* __restrict__ lam_p,
    const float* __restrict__ subln,         // 128
    unsigned short* __restrict__ O) {        // (B,T,2048) bf16
  const int bx = blockIdx.x, h = blockIdx.y, b = blockIdx.z;
  const int tid = threadIdx.x;
  const int lane = tid & 63, w = tid >> 6;
  const int lg = lane >> 4, cc = lane & 15;
  const int hh = w >> 1, qoff = (w & 1) * 16;

  __shared__ __align__(16) unsigned short KsBuf[2 * 64 * 64];  // [hh][k][d] swizzled; reused as comb f32[32][128]
  __shared__ __align__(16) unsigned short VsBuf[128 * 64];     // [c][k] swizzled
  __shared__ __align__(16) unsigned short PbBuf[4 * 16 * 64];  // per-wave P, swizzled

  const float lam = lam_p[0];
  char* ksb = reinterpret_cast<char*>(KsBuf);
  char* vsb = reinterpret_cast<char*>(VsBuf);
  char* pbb = reinterpret_cast<char*>(PbBuf) + w * 2048;
  float* cb = reinterpret_cast<float*>(KsBuf);

  float sl[8];
  #pragma unroll
  for (int jc = 0; jc < 8; ++jc) sl[jc] = subln[jc * 16 + cc];

  const long kbase = (long)((b * 32 + 2 * h + hh) * 1024);

  for (int pass = 0; pass < 2; ++pass) {
    const int q0 = (pass ? (31 - bx) : bx) * 32;
    const int nt = ((q0 + 31) >> 6) + 1;

    // Q fragments for this pass (A-frag row = cc within wave's 16-row subtile)
    bf16x8 qf[2];
    {
      const long qrow = q0 + qoff + cc;
      #pragma unroll
      for (int c = 0; c < 2; ++c)
        qf[c] = *reinterpret_cast<const bf16x8*>(&Qa[(kbase + qrow) * 64 + c * 32 + lg * 8]);
    }
    f32x4 acc_o[8];
    float mS[4], lS[4];
    #pragma unroll
    for (int jc = 0; jc < 8; ++jc) acc_o[jc] = (f32x4){0.f, 0.f, 0.f, 0.f};
    #pragma unroll
    for (int r = 0; r < 4; ++r) { mS[r] = -1e30f; lS[r] = 0.f; }

    for (int tile = 0; tile < nt; ++tile) {
      const int k0 = tile * 64;
      __syncthreads();  // all waves done reading ksb/vsb (prev tile or prev-pass epilogue)
      // stage K: 2 sub-heads x 64 rows x 64 d, uint4 (16B) per slot
      #pragma unroll
      for (int p = 0; p < 4; ++p) {
        int idx = p * 256 + tid;  // 0..1023
        int sh = idx >> 9;
        int kk = (idx >> 3) & 63;
        int j8 = idx & 7;
        uint4 vld = *reinterpret_cast<const uint4*>(
            &Ka[((long)((b * 32 + 2 * h + sh) * 1024) + k0 + kk) * 64 + j8 * 8]);
        *reinterpret_cast<uint4*>(ksb + sh * 8192 + kk * 128 + SWZB(kk, j8 * 16)) = vld;
      }
      // stage V^T tile: 128 channel-rows x 64 k, uint4
      #pragma unroll
      for (int p = 0; p < 4; ++p) {
        int idx = p * 256 + tid;  // 0..1023
        int cr = idx >> 3;        // 0..127
        int j8 = idx & 7;
        uint4 vld = *reinterpret_cast<const uint4*>(
            &Vt[((long)(b * 2048 + h * 128 + cr)) * 1024 + k0 + j8 * 8]);
        *reinterpret_cast<uint4*>(vsb + cr * 128 + SWZB(cr, j8 * 16)) = vld;
      }
      __syncthreads();

      // ---- QK^T ----
      f32x4 s4[4];
      #pragma unroll
      for (int j = 0; j < 4; ++j) s4[j] = (f32x4){0.f, 0.f, 0.f, 0.f};
      #pragma unroll
      for (int j = 0; j < 4; ++j) {
        int row = j * 16 + cc;
        const char* base = ksb + hh * 8192 + row * 128;
        bf16x8 kb0 = *reinterpret_cast<const bf16x8*>(base + SWZB(row, lg * 16));
        bf16x8 kb1 = *reinterpret_cast<const bf16x8*>(base + SWZB(row, lg * 16 + 64));
        s4[j] = __builtin_amdgcn_mfma_f32_16x16x32_bf16(qf[0], kb0, s4[j], 0, 0, 0);
        s4[j] = __builtin_amdgcn_mfma_f32_16x16x32_bf16(qf[1], kb1, s4[j], 0, 0, 0);
      }
      // scale + causal mask
      #pragma unroll
      for (int j = 0; j < 4; ++j) {
        int kcol = k0 + j * 16 + cc;
        #pragma unroll
        for (int r = 0; r < 4; ++r) {
          int qrow = q0 + qoff + lg * 4 + r;
          float s = s4[j][r] * 0.125f;
          s4[j][r] = (kcol > qrow) ? -1e30f : s;
        }
      }
      // online softmax (row-reduce over 16-lane col group)
      float rescv[4];
      #pragma unroll
      for (int r = 0; r < 4; ++r) {
        float mx = fmaxf(fmaxf(s4[0][r], s4[1][r]), fmaxf(s4[2][r], s4[3][r]));
        mx = fmaxf(mx, __shfl_xor(mx, 1));
        mx = fmaxf(mx, __shfl_xor(mx, 2));
        mx = fmaxf(mx, __shfl_xor(mx, 4));
        mx = fmaxf(mx, __shfl_xor(mx, 8));
        float mold = mS[r];
        float mnew = fmaxf(mold, mx);
        mS[r] = mnew;
        float rsc = __expf(mold - mnew);
        rescv[r] = rsc;
        float ls = 0.f;
        #pragma unroll
        for (int j = 0; j < 4; ++j) {
          float p = __expf(s4[j][r] - mnew);  // masked -> 0
          s4[j][r] = p;
          ls += p;
        }
        ls += __shfl_xor(ls, 1);
        ls += __shfl_xor(ls, 2);
        ls += __shfl_xor(ls, 4);
        ls += __shfl_xor(ls, 8);
        lS[r] = lS[r] * rsc + ls;
      }
      // write P (bf16) into wave-private swizzled buffer (no barrier needed)
      #pragma unroll
      for (int j = 0; j < 4; ++j)
        #pragma unroll
        for (int r = 0; r < 4; ++r) {
          int rowl = lg * 4 + r;
          *reinterpret_cast<unsigned short*>(
              pbb + rowl * 128 + SWZB(rowl, (j * 16 + cc) * 2)) = f2bf(s4[j][r]);
        }

      // ---- PV ----
      bf16x8 pa[2];
      #pragma unroll
      for (int c = 0; c < 2; ++c)
        pa[c] = *reinterpret_cast<const bf16x8*>(pbb + cc * 128 + SWZB(cc, lg * 16 + c * 64));
      #pragma unroll
      for (int jc = 0; jc < 8; ++jc)
        #pragma unroll
        for (int r = 0; r < 4; ++r)
          acc_o[jc][r] *= rescv[r];
      #pragma unroll
      for (int jc = 0; jc < 8; ++jc) {
        int row = jc * 16 + cc;
        const char* base = vsb + row * 128;
        bf16x8 vf0 = *reinterpret_cast<const bf16x8*>(base + SWZB(row, lg * 16));
        bf16x8 vf1 = *reinterpret_cast<const bf16x8*>(base + SWZB(row, lg * 16 + 64));
        acc_o[jc] = __builtin_amdgcn_mfma_f32_16x16x32_bf16(pa[0], vf0, acc_o[jc], 0, 0, 0);
        acc_o[jc] = __builtin_amdgcn_mfma_f32_16x16x32_bf16(pa[1], vf1, acc_o[jc], 0, 0, 0);
      }
    }

    // ---- pass epilogue: cross-wave diff combine + RMS + subln + store ----
    __syncthreads();  // all waves done reading ksb (QK of last tile)
    if (hh == 1) {
      #pragma unroll
      for (int r = 0; r < 4; ++r) {
        float inv2 = lam / lS[r];
        int row = qoff + lg * 4 + r;
        #pragma unroll
        for (int jc = 0; jc < 8; ++jc)
          cb[row * 128 + ((jc ^ (row & 7)) * 16 + cc)] = acc_o[jc][r] * inv2;
      }
    }
    __syncthreads();
    if (hh == 0) {
      float sc[4];
      #pragma unroll
      for (int r = 0; r < 4; ++r) {
        float inv1 = 1.f / lS[r];
        int row = qoff + lg * 4 + r;
        float ss = 0.f;
        #pragma unroll
        for (int jc = 0; jc < 8; ++jc) {
          float at = acc_o[jc][r] * inv1 - cb[row * 128 + ((jc ^ (row & 7)) * 16 + cc)];
          acc_o[jc][r] = at;
          ss += at * at;
        }
        ss += __shfl_xor(ss, 1);
        ss += __shfl_xor(ss, 2);
        ss += __shfl_xor(ss, 4);
        ss += __shfl_xor(ss, 8);
        sc[r] = rsqrtf(ss * (1.f / 128.f) + 1e-5f);
      }
      #pragma unroll
      for (int r = 0; r < 4; ++r) {
        long qrow = q0 + qoff + lg * 4 + r;
        #pragma unroll
        for (int jc = 0; jc < 8; ++jc) {
          O[(long)(b * 1024 + qrow) * 2048 + h * 128 + jc * 16 + cc] =
              f2bf(acc_o[jc][r] * sc[r] * sl[jc]);
        }
      }
    }
  }
}

extern "C" void kernel_launch(void* const* d_in, const int* in_sizes, int n_in,
                              void* d_out, int out_size, void* d_ws, size_t ws_size,
                              hipStream_t stream) {
  (void)in_sizes; (void)n_in; (void)out_size; (void)ws_size;
  const float* x    = (const float*)d_in[0];
  const float* rel  = (const float*)d_in[1];
  const float* wq   = (const float*)d_in[2];
  const float* wk   = (const float*)d_in[3];
  const float* wv   = (const float*)d_in[4];
  const float* lq1  = (const float*)d_in[5];
  const float* lq2  = (const float*)d_in[6];
  const float* lk1  = (const float*)d_in[7];
  const float* lk2  = (const float*)d_in[8];
  const float* subw = (const float*)d_in[9];
  const float* wo   = (const float*)d_in[10];
  float* out = (float*)d_out;

  char* ws = (char*)d_ws;
  const size_t SZ = (size_t)2048 * 2048 * 2;  // 8 MB (bf16 2048x2048)
  unsigned short* qraw = (unsigned short*)(ws);
  unsigned short* kraw = (unsigned short*)(ws + SZ);
  unsigned short* vraw = (unsigned short*)(ws + 2 * SZ);
  unsigned short* qatt = (unsigned short*)(ws + 3 * SZ);
  unsigned short* katt = (unsigned short*)(ws + 4 * SZ);
  float* lamb          = (float*)(ws + 5 * SZ);
  unsigned short* vtb  = kraw;  // kraw dead after rope(k)
  unsigned short* aout = qraw;  // qraw dead after rope(q)

  // LAMBDA_INIT = 0.8 - 0.6*exp(-0.3*12)
  lambda_kernel<<<1, 64, 0, stream>>>(lq1, lq2, lk1, lk2, lamb, 0.7836057665316245f);

  dim3 gg(16, 16);
  gemm_bt<float, float, unsigned short><<<gg, 256, 0, stream>>>(x, wq, qraw, 2048, 2048, 2048);
  gemm_bt<float, float, unsigned short><<<gg, 256, 0, stream>>>(x, wk, kraw, 2048, 2048, 2048);
  gemm_bt<float, float, unsigned short><<<gg, 256, 0, stream>>>(x, wv, vraw, 2048, 2048, 2048);

  rope_kernel<<<8192, 256, 0, stream>>>(qraw, rel, qatt, 0);
  rope_kernel<<<8192, 256, 0, stream>>>(kraw, rel, katt, 1);

  transpose_v<<<dim3(16, 32, 2), 256, 0, stream>>>(vraw, vtb);

  attn_mfma<<<dim3(16, 16, 2), 256, 0, stream>>>(qatt, katt, vtb, lamb, subw, aout);

  gemm_bt<unsigned short, float, float><<<gg, 256, 0, stream>>>(aout, wo, out, 2048, 2048, 2048);
}

// Round 8
// 247.544 us; speedup vs baseline: 8.6336x; 1.7440x over previous
//
#include <hip/hip_runtime.h>

typedef __bf16 bf16x8 __attribute__((ext_vector_type(8)));
typedef float f32x4 __attribute__((ext_vector_type(4)));

__device__ __forceinline__ float bf2f(unsigned short u) {
  return __uint_as_float(((unsigned)u) << 16);
}
__device__ __forceinline__ unsigned short f2bf(float f) {
  unsigned u = __float_as_uint(f);
  return (unsigned short)((u + 0x7fffu + ((u >> 16) & 1u)) >> 16);
}
__device__ __forceinline__ unsigned pack2(float a, float b) {
  return (unsigned)f2bf(a) | ((unsigned)f2bf(b) << 16);
}

// XOR swizzle on 16B blocks within a 128B row (T2 / Guideline 4).
#define SWZB(row, byte) ((byte) ^ (((row) & 7) << 4))

#define AS_GLOBAL(p) ((const __attribute__((address_space(1))) void*)(p))
#define AS_LDS(p) ((__attribute__((address_space(3))) void*)(p))

// ---------------- lambda scalar ----------------
__global__ void lambda_kernel(const float* __restrict__ lq1, const float* __restrict__ lq2,
                              const float* __restrict__ lk1, const float* __restrict__ lk2,
                              float* __restrict__ out, float lam_init) {
  int l = threadIdx.x;
  float p1 = lq1[l] * lk1[l];
  float p2 = lq2[l] * lk2[l];
  #pragma unroll
  for (int off = 32; off; off >>= 1) {
    p1 += __shfl_xor(p1, off);
    p2 += __shfl_xor(p2, off);
  }
  if (l == 0) out[0] = expf(p1) - expf(p2) + lam_init;
}

// ---------------- fp32 -> bf16 convert (vectorized, one-shot) ----------------
__global__ __launch_bounds__(256) void cvt_f32_bf16(const float* __restrict__ in,
                                                    unsigned short* __restrict__ out, int n4) {
  int idx = blockIdx.x * 256 + threadIdx.x;
  if (idx >= n4) return;
  float4 v = reinterpret_cast<const float4*>(in)[idx];
  uint2 pk;
  pk.x = pack2(v.x, v.y);
  pk.y = pack2(v.z, v.w);
  reinterpret_cast<uint2*>(out)[idx] = pk;
}

// ---------------- GEMM (bf16 x bf16): C[m][n] = sum_k A[m][k] * Bw[n][k] ----------------
// m97-structure: 128x128 tile, BK=32, 4 waves 2x2, 4x4 frags, global_load_lds width-16.
// Bw may have more rows than ldc (fused QKV): out base = C + (bn/ldc)*M*ldc + bn%ldc.
template <typename OT>
__global__ __launch_bounds__(256)
void gemm_lds(const unsigned short* __restrict__ A, const unsigned short* __restrict__ Bw,
              OT* __restrict__ C, int M, int K, int ldc) {
  __shared__ __align__(16) unsigned short As[128 * 32];
  __shared__ __align__(16) unsigned short Bs[128 * 32];
  const int tid = threadIdx.x;
  const int bm = blockIdx.x * 128, bn = blockIdx.y * 128;
  const int lane = tid & 63, wave = tid >> 6;
  const int wm = (wave >> 1) * 64, wn = (wave & 1) * 64;
  const int kf = (lane >> 4) * 8, rr = lane & 15;
  const int ldrow = lane >> 2, ldk = (lane & 3) * 8;  // 4 lanes/row x 8 elems = BK
  OT* Cb = C + (size_t)(bn / ldc) * ((size_t)M * ldc) + (bn % ldc);
  f32x4 acc[4][4] = {};
  for (int kt = 0; kt < K; kt += 32) {
    __syncthreads();
    // stage A,B tiles: wave-uniform LDS base + lane*16 (HW), per-lane global src.
    #pragma unroll
    for (int i = 0; i < 2; ++i) {
      int row = (i * 4 + wave) * 16 + ldrow;
      __builtin_amdgcn_global_load_lds(AS_GLOBAL(&A[(long)(bm + row) * K + kt + ldk]),
                                       AS_LDS(&As[(i * 4 + wave) * 512]), 16, 0, 0);
      __builtin_amdgcn_global_load_lds(AS_GLOBAL(&Bw[(long)(bn + row) * K + kt + ldk]),
                                       AS_LDS(&Bs[(i * 4 + wave) * 512]), 16, 0, 0);
    }
    __syncthreads();  // compiler emits vmcnt(0) drain here
    bf16x8 af[4], bq[4];
    #pragma unroll
    for (int i = 0; i < 4; ++i)
      af[i] = *reinterpret_cast<const bf16x8*>(&As[(wm + i * 16 + rr) * 32 + kf]);
    #pragma unroll
    for (int j = 0; j < 4; ++j)
      bq[j] = *reinterpret_cast<const bf16x8*>(&Bs[(wn + j * 16 + rr) * 32 + kf]);
    #pragma unroll
    for (int i = 0; i < 4; ++i)
      #pragma unroll
      for (int j = 0; j < 4; ++j)
        acc[i][j] = __builtin_amdgcn_mfma_f32_16x16x32_bf16(af[i], bq[j], acc[i][j], 0, 0, 0);
  }
  const int r0 = (lane >> 4) * 4, c0 = lane & 15;
  #pragma unroll
  for (int i = 0; i < 4; ++i)
    #pragma unroll
    for (int j = 0; j < 4; ++j) {
      #pragma unroll
      for (int r = 0; r < 4; ++r) {
        long row = bm + wm + i * 16 + r0 + r;
        long col = wn + j * 16 + c0;
        float v = acc[i][j][r];
        if constexpr (sizeof(OT) == 2) Cb[row * ldc + col] = f2bf(v);
        else                           Cb[row * ldc + col] = v;
      }
    }
}

// ---------------- RoPE (+optional rel_pos pre-scale), with transpose ----------------
__global__ __launch_bounds__(256) void rope_kernel(const unsigned short* __restrict__ raw,
                                                   const float* __restrict__ rel,
                                                   unsigned short* __restrict__ out,
                                                   int use_rel) {
  int idx = blockIdx.x * 256 + threadIdx.x;  // 2^21 total
  int i = idx & 31;
  int t = (idx >> 5) & 1023;
  int hp = (idx >> 15) & 31;
  int b = idx >> 20;
  int src = (b * 1024 + t) * 2048 + hp * 64 + 2 * i;
  unsigned pair = *reinterpret_cast<const unsigned*>(&raw[src]);
  float x1 = __uint_as_float(pair << 16);
  float x2 = __uint_as_float(pair & 0xffff0000u);
  if (use_rel) {
    x1 *= rel[t * 64 + 2 * i];
    x2 *= rel[t * 64 + 2 * i + 1];
  }
  float inv = expf(-0.28782313662425574f * (float)i);  // 10000^(-2i/64)
  float ang = (float)t * inv;
  float s, c;
  sincosf(ang, &s, &c);
  float r1 = x1 * c - x2 * s;
  float r2 = x1 * s + x2 * c;
  int dst = ((b * 32 + hp) * 1024 + t) * 64 + 2 * i;
  *reinterpret_cast<unsigned*>(&out[dst]) = pack2(r1, r2);
}

// ---------------- V transpose: (b, t, 2048) -> (b, n, 1024) ----------------
__global__ __launch_bounds__(256) void transpose_v(const unsigned short* __restrict__ in,
                                                   unsigned short* __restrict__ out) {
  __shared__ unsigned short ls[64][68];
  const int t0 = blockIdx.x * 64, n0 = blockIdx.y * 64, b = blockIdx.z;
  const int tid = threadIdx.x;
  #pragma unroll
  for (int p = 0; p < 4; ++p) {
    int idx = p * 256 + tid;
    int tl = idx >> 4, nq = (idx & 15) * 4;
    *reinterpret_cast<uint2*>(&ls[tl][nq]) = *reinterpret_cast<const uint2*>(
        &in[((long)(b * 1024 + t0 + tl)) * 2048 + n0 + nq]);
  }
  __syncthreads();
  #pragma unroll
  for (int p = 0; p < 4; ++p) {
    int idx = p * 256 + tid;
    int nl = idx >> 4, tq = (idx & 15) * 4;
    unsigned short a0 = ls[tq + 0][nl], a1 = ls[tq + 1][nl];
    unsigned short a2 = ls[tq + 2][nl], a3 = ls[tq + 3][nl];
    uint2 o;
    o.x = (unsigned)a0 | ((unsigned)a1 << 16);
    o.y = (unsigned)a2 | ((unsigned)a3 << 16);
    *reinterpret_cast<uint2*>(&out[((long)(b * 2048 + n0 + nl)) * 1024 + t0 + tq]) = o;
  }
}

// ---------------- MFMA differential flash attention + fused sub-LN ----------------
// Balanced 2-pass blocks: block bx processes 32-row q-subtiles {bx, 31-bx} -> every
// block does exactly 17 K-tile iterations (causal work sum is constant).
// 4 waves: wave w owns (16 q-rows qoff=(w&1)*16, sub-head hh=w>>1). P is wave-private
// (2KB each) -> only 2 barriers per tile-iter. Epilogue: hh1 waves deposit lam/l2*o2
// into LDS (reusing K buffer, jc^row swizzle), hh0 waves combine + RMS + subln + store.
__global__ __launch_bounds__(256) void attn_mfma(
    const unsigned short* __restrict__ Qa,   // (B,32,T,64) bf16
    const unsigned short* __restrict__ Ka,   // (B,32,T,64) bf16
    const unsigned short* __restrict__ Vt,   // (B,2048,T) bf16 (V transposed)
    const float* __restrict__ lam_p,
    const float* __restrict__ subln,         // 128
    unsigned short* __restrict__ O) {        // (B,T,2048) bf16
  const int bx = blockIdx.x, h = blockIdx.y, b = blockIdx.z;
  const int tid = threadIdx.x;
  const int lane = tid & 63, w = tid >> 6;
  const int lg = lane >> 4, cc = lane & 15;
  const int hh = w >> 1, qoff = (w & 1) * 16;

  __shared__ __align__(16) unsigned short KsBuf[2 * 64 * 64];  // [hh][k][d] swizzled; reused as comb f32[32][128]
  __shared__ __align__(16) unsigned short VsBuf[128 * 64];     // [c][k] swizzled
  __shared__ __align__(16) unsigned short PbBuf[4 * 16 * 64];  // per-wave P, swizzled

  const float lam = lam_p[0];
  char* ksb = reinterpret_cast<char*>(KsBuf);
  char* vsb = reinterpret_cast<char*>(VsBuf);
  char* pbb = reinterpret_cast<char*>(PbBuf) + w * 2048;
  float* cb = reinterpret_cast<float*>(KsBuf);

  float sl[8];
  #pragma unroll
  for (int jc = 0; jc < 8; ++jc) sl[jc] = subln[jc * 16 + cc];

  const long kbase = (long)((b * 32 + 2 * h + hh) * 1024);

  for (int pass = 0; pass < 2; ++pass) {
    const int q0 = (pass ? (31 - bx) : bx) * 32;
    const int nt = ((q0 + 31) >> 6) + 1;

    // Q fragments for this pass (A-frag row = cc within wave's 16-row subtile)
    bf16x8 qf[2];
    {
      const long qrow = q0 + qoff + cc;
      #pragma unroll
      for (int c = 0; c < 2; ++c)
        qf[c] = *reinterpret_cast<const bf16x8*>(&Qa[(kbase + qrow) * 64 + c * 32 + lg * 8]);
    }
    f32x4 acc_o[8];
    float mS[4], lS[4];
    #pragma unroll
    for (int jc = 0; jc < 8; ++jc) acc_o[jc] = (f32x4){0.f, 0.f, 0.f, 0.f};
    #pragma unroll
    for (int r = 0; r < 4; ++r) { mS[r] = -1e30f; lS[r] = 0.f; }

    for (int tile = 0; tile < nt; ++tile) {
      const int k0 = tile * 64;
      __syncthreads();  // all waves done reading ksb/vsb (prev tile or prev-pass epilogue)
      // stage K: 2 sub-heads x 64 rows x 64 d, uint4 (16B) per slot
      #pragma unroll
      for (int p = 0; p < 4; ++p) {
        int idx = p * 256 + tid;  // 0..1023
        int sh = idx >> 9;
        int kk = (idx >> 3) & 63;
        int j8 = idx & 7;
        uint4 vld = *reinterpret_cast<const uint4*>(
            &Ka[((long)((b * 32 + 2 * h + sh) * 1024) + k0 + kk) * 64 + j8 * 8]);
        *reinterpret_cast<uint4*>(ksb + sh * 8192 + kk * 128 + SWZB(kk, j8 * 16)) = vld;
      }
      // stage V^T tile: 128 channel-rows x 64 k, uint4
      #pragma unroll
      for (int p = 0; p < 4; ++p) {
        int idx = p * 256 + tid;  // 0..1023
        int cr = idx >> 3;        // 0..127
        int j8 = idx & 7;
        uint4 vld = *reinterpret_cast<const uint4*>(
            &Vt[((long)(b * 2048 + h * 128 + cr)) * 1024 + k0 + j8 * 8]);
        *reinterpret_cast<uint4*>(vsb + cr * 128 + SWZB(cr, j8 * 16)) = vld;
      }
      __syncthreads();

      // ---- QK^T ----
      f32x4 s4[4];
      #pragma unroll
      for (int j = 0; j < 4; ++j) s4[j] = (f32x4){0.f, 0.f, 0.f, 0.f};
      #pragma unroll
      for (int j = 0; j < 4; ++j) {
        int row = j * 16 + cc;
        const char* base = ksb + hh * 8192 + row * 128;
        bf16x8 kb0 = *reinterpret_cast<const bf16x8*>(base + SWZB(row, lg * 16));
        bf16x8 kb1 = *reinterpret_cast<const bf16x8*>(base + SWZB(row, lg * 16 + 64));
        s4[j] = __builtin_amdgcn_mfma_f32_16x16x32_bf16(qf[0], kb0, s4[j], 0, 0, 0);
        s4[j] = __builtin_amdgcn_mfma_f32_16x16x32_bf16(qf[1], kb1, s4[j], 0, 0, 0);
      }
      // scale + causal mask
      #pragma unroll
      for (int j = 0; j < 4; ++j) {
        int kcol = k0 + j * 16 + cc;
        #pragma unroll
        for (int r = 0; r < 4; ++r) {
          int qrow = q0 + qoff + lg * 4 + r;
          float s = s4[j][r] * 0.125f;
          s4[j][r] = (kcol > qrow) ? -1e30f : s;
        }
      }
      // online softmax (row-reduce over 16-lane col group)
      float rescv[4];
      #pragma unroll
      for (int r = 0; r < 4; ++r) {
        float mx = fmaxf(fmaxf(s4[0][r], s4[1][r]), fmaxf(s4[2][r], s4[3][r]));
        mx = fmaxf(mx, __shfl_xor(mx, 1));
        mx = fmaxf(mx, __shfl_xor(mx, 2));
        mx = fmaxf(mx, __shfl_xor(mx, 4));
        mx = fmaxf(mx, __shfl_xor(mx, 8));
        float mold = mS[r];
        float mnew = fmaxf(mold, mx);
        mS[r] = mnew;
        float rsc = __expf(mold - mnew);
        rescv[r] = rsc;
        float ls = 0.f;
        #pragma unroll
        for (int j = 0; j < 4; ++j) {
          float p = __expf(s4[j][r] - mnew);  // masked -> 0
          s4[j][r] = p;
          ls += p;
        }
        ls += __shfl_xor(ls, 1);
        ls += __shfl_xor(ls, 2);
        ls += __shfl_xor(ls, 4);
        ls += __shfl_xor(ls, 8);
        lS[r] = lS[r] * rsc + ls;
      }
      // write P (bf16) into wave-private swizzled buffer (no barrier needed)
      #pragma unroll
      for (int j = 0; j < 4; ++j)
        #pragma unroll
        for (int r = 0; r < 4; ++r) {
          int rowl = lg * 4 + r;
          *reinterpret_cast<unsigned short*>(
              pbb + rowl * 128 + SWZB(rowl, (j * 16 + cc) * 2)) = f2bf(s4[j][r]);
        }

      // ---- PV ----
      bf16x8 pa[2];
      #pragma unroll
      for (int c = 0; c < 2; ++c)
        pa[c] = *reinterpret_cast<const bf16x8*>(pbb + cc * 128 + SWZB(cc, lg * 16 + c * 64));
      #pragma unroll
      for (int jc = 0; jc < 8; ++jc)
        #pragma unroll
        for (int r = 0; r < 4; ++r)
          acc_o[jc][r] *= rescv[r];
      #pragma unroll
      for (int jc = 0; jc < 8; ++jc) {
        int row = jc * 16 + cc;
        const char* base = vsb + row * 128;
        bf16x8 vf0 = *reinterpret_cast<const bf16x8*>(base + SWZB(row, lg * 16));
        bf16x8 vf1 = *reinterpret_cast<const bf16x8*>(base + SWZB(row, lg * 16 + 64));
        acc_o[jc] = __builtin_amdgcn_mfma_f32_16x16x32_bf16(pa[0], vf0, acc_o[jc], 0, 0, 0);
        acc_o[jc] = __builtin_amdgcn_mfma_f32_16x16x32_bf16(pa[1], vf1, acc_o[jc], 0, 0, 0);
      }
    }

    // ---- pass epilogue: cross-wave diff combine + RMS + subln + store ----
    __syncthreads();  // all waves done reading ksb (QK of last tile)
    if (hh == 1) {
      #pragma unroll
      for (int r = 0; r < 4; ++r) {
        float inv2 = lam / lS[r];
        int row = qoff + lg * 4 + r;
        #pragma unroll
        for (int jc = 0; jc < 8; ++jc)
          cb[row * 128 + ((jc ^ (row & 7)) * 16 + cc)] = acc_o[jc][r] * inv2;
      }
    }
    __syncthreads();
    if (hh == 0) {
      float sc[4];
      #pragma unroll
      for (int r = 0; r < 4; ++r) {
        float inv1 = 1.f / lS[r];
        int row = qoff + lg * 4 + r;
        float ss = 0.f;
        #pragma unroll
        for (int jc = 0; jc < 8; ++jc) {
          float at = acc_o[jc][r] * inv1 - cb[row * 128 + ((jc ^ (row & 7)) * 16 + cc)];
          acc_o[jc][r] = at;
          ss += at * at;
        }
        ss += __shfl_xor(ss, 1);
        ss += __shfl_xor(ss, 2);
        ss += __shfl_xor(ss, 4);
        ss += __shfl_xor(ss, 8);
        sc[r] = rsqrtf(ss * (1.f / 128.f) + 1e-5f);
      }
      #pragma unroll
      for (int r = 0; r < 4; ++r) {
        long qrow = q0 + qoff + lg * 4 + r;
        #pragma unroll
        for (int jc = 0; jc < 8; ++jc) {
          O[(long)(b * 1024 + qrow) * 2048 + h * 128 + jc * 16 + cc] =
              f2bf(acc_o[jc][r] * sc[r] * sl[jc]);
        }
      }
    }
  }
}

extern "C" void kernel_launch(void* const* d_in, const int* in_sizes, int n_in,
                              void* d_out, int out_size, void* d_ws, size_t ws_size,
                              hipStream_t stream) {
  (void)in_sizes; (void)n_in; (void)out_size; (void)ws_size;
  const float* x    = (const float*)d_in[0];
  const float* rel  = (const float*)d_in[1];
  const float* wq   = (const float*)d_in[2];
  const float* wk   = (const float*)d_in[3];
  const float* wv   = (const float*)d_in[4];
  const float* lq1  = (const float*)d_in[5];
  const float* lq2  = (const float*)d_in[6];
  const float* lk1  = (const float*)d_in[7];
  const float* lk2  = (const float*)d_in[8];
  const float* subw = (const float*)d_in[9];
  const float* wo   = (const float*)d_in[10];
  float* out = (float*)d_out;

  char* ws = (char*)d_ws;
  const size_t SZ = (size_t)2048 * 2048 * 2;  // 8 MB (bf16 2048x2048)
  // Layout (liveness-ordered):
  //   [0..3SZ): qraw|kraw|vraw (contiguous: fused QKV GEMM output, proj-major)
  //   [3SZ):    xbf
  //   [4SZ..7SZ): wqkvbf (during QKV GEMM); then reused as qatt|katt|wobf
  unsigned short* qraw  = (unsigned short*)(ws);
  unsigned short* kraw  = (unsigned short*)(ws + SZ);
  unsigned short* vraw  = (unsigned short*)(ws + 2 * SZ);
  unsigned short* xbf   = (unsigned short*)(ws + 3 * SZ);
  unsigned short* wqkvb = (unsigned short*)(ws + 4 * SZ);
  unsigned short* qatt  = (unsigned short*)(ws + 4 * SZ);
  unsigned short* katt  = (unsigned short*)(ws + 5 * SZ);
  unsigned short* wob   = (unsigned short*)(ws + 6 * SZ);
  float* lamb           = (float*)(ws + 7 * SZ);
  unsigned short* vtb  = kraw;  // kraw dead after rope(k)
  unsigned short* aout = qraw;  // qraw dead after rope(q)

  // LAMBDA_INIT = 0.8 - 0.6*exp(-0.3*12)
  lambda_kernel<<<1, 64, 0, stream>>>(lq1, lq2, lk1, lk2, lamb, 0.7836057665316245f);

  const int N4 = 2048 * 2048 / 4;
  cvt_f32_bf16<<<N4 / 256, 256, 0, stream>>>(x, xbf, N4);
  cvt_f32_bf16<<<N4 / 256, 256, 0, stream>>>(wq, wqkvb, N4);
  cvt_f32_bf16<<<N4 / 256, 256, 0, stream>>>(wk, wqkvb + (size_t)2048 * 2048, N4);
  cvt_f32_bf16<<<N4 / 256, 256, 0, stream>>>(wv, wqkvb + (size_t)2 * 2048 * 2048, N4);

  // fused QKV projection: M=2048, N=6144 (q|k|v), K=2048 -> 768 blocks
  gemm_lds<unsigned short><<<dim3(16, 48), 256, 0, stream>>>(xbf, wqkvb, qraw, 2048, 2048, 2048);

  rope_kernel<<<8192, 256, 0, stream>>>(qraw, rel, qatt, 0);
  rope_kernel<<<8192, 256, 0, stream>>>(kraw, rel, katt, 1);
  cvt_f32_bf16<<<N4 / 256, 256, 0, stream>>>(wo, wob, N4);  // after QKV GEMM (region reuse)

  transpose_v<<<dim3(16, 32, 2), 256, 0, stream>>>(vraw, vtb);

  attn_mfma<<<dim3(16, 16, 2), 256, 0, stream>>>(qatt, katt, vtb, lamb, subw, aout);

  gemm_lds<float><<<dim3(16, 16), 256, 0, stream>>>(aout, wob, out, 2048, 2048, 2048);
}